// Round 1
// baseline (15707.527 us; speedup 1.0000x reference)
//
#include <hip/hip_runtime.h>

#define D 128

// ---------------------------------------------------------------------------
// degree histogram: deg[dst] += 1 per edge
// ---------------------------------------------------------------------------
__global__ void deg_kernel(const int* __restrict__ dst, float* __restrict__ deg, int E) {
  int i = blockIdx.x * blockDim.x + threadIdx.x;
  int stride = gridDim.x * blockDim.x;
  for (int e = i; e < E; e += stride)
    atomicAdd(&deg[dst[e]], 1.0f);
}

// dinv = rsqrt(deg+1), dinv2 = dinv^2 (self-loop coefficient)
__global__ void dinv_kernel(const float* __restrict__ deg, float* __restrict__ dinv,
                            float* __restrict__ dinv2, int n) {
  int i = blockIdx.x * blockDim.x + threadIdx.x;
  if (i < n) {
    float r = rsqrtf(deg[i] + 1.0f);
    dinv[i] = r;
    dinv2[i] = r * r;
  }
}

// ---------------------------------------------------------------------------
// pass A over edges: one wave per edge, lane l covers feature 2l,2l+1
//   aggGin[d] += x[s]            (GIN conv1 aggregation)
//   aggGcn[d] += norm(s,d)*x[s]  (GCN conv1 aggregation, pre-matmul)
// ---------------------------------------------------------------------------
__global__ __launch_bounds__(256) void passA_kernel(
    const float* __restrict__ x, const float* __restrict__ dinv,
    const int* __restrict__ src, const int* __restrict__ dst,
    float* __restrict__ aggGin, float* __restrict__ aggGcn, int E) {
  int wave = blockIdx.x * (blockDim.x >> 6) + (threadIdx.x >> 6);
  int lane = threadIdx.x & 63;
  int nw = gridDim.x * (blockDim.x >> 6);
  for (int e = wave; e < E; e += nw) {
    int s = src[e], d = dst[e];
    float ns = dinv[s] * dinv[d];
    float2 v = *(const float2*)(x + s * D + 2 * lane);
    float* pg = aggGin + d * D + 2 * lane;
    float* pc = aggGcn + d * D + 2 * lane;
    atomicAdd(pg + 0, v.x);
    atomicAdd(pg + 1, v.y);
    atomicAdd(pc + 0, ns * v.x);
    atomicAdd(pc + 1, ns * v.y);
  }
}

// pass B over edges: aggGcn1[d] += norm*h[s];  aggGin1[d] += g[s]
__global__ __launch_bounds__(256) void passB_kernel(
    const float* __restrict__ h, const float* __restrict__ g,
    const float* __restrict__ dinv,
    const int* __restrict__ src, const int* __restrict__ dst,
    float* __restrict__ aggGcn, float* __restrict__ aggGin, int E) {
  int wave = blockIdx.x * (blockDim.x >> 6) + (threadIdx.x >> 6);
  int lane = threadIdx.x & 63;
  int nw = gridDim.x * (blockDim.x >> 6);
  for (int e = wave; e < E; e += nw) {
    int s = src[e], d = dst[e];
    float ns = dinv[s] * dinv[d];
    float2 vh = *(const float2*)(h + s * D + 2 * lane);
    float2 vg = *(const float2*)(g + s * D + 2 * lane);
    float* pc = aggGcn + d * D + 2 * lane;
    float* pg = aggGin + d * D + 2 * lane;
    atomicAdd(pc + 0, ns * vh.x);
    atomicAdd(pc + 1, ns * vh.y);
    atomicAdd(pg + 0, vg.x);
    atomicAdd(pg + 1, vg.y);
  }
}

// ---------------------------------------------------------------------------
// GEMM: out[r][c] = f( (A1[r] + rowscale[r]*A2[r]) @ W + bscale*bias [+ out] )
// block tile 64 rows x 64 cols, 256 threads, 4x4 register tile per thread.
// As rotation-swizzled so per-k row reads hit distinct banks; k-loop fully
// unrolled so all LDS offsets are immediates.
// ---------------------------------------------------------------------------
template <bool RELU, bool ACCUM, bool HAS_A2>
__global__ __launch_bounds__(256, 2) void gemm_kernel(
    const float* __restrict__ A1, const float* __restrict__ A2,
    const float* __restrict__ rowscale, const float* __restrict__ W,
    const float* __restrict__ bias, float bscale,
    float* __restrict__ out, int n) {
  __shared__ float As[64 * D];  // 32 KB, swizzled [r][(k + 8*(r&3)) & 127]
  __shared__ float Ws[D * 64];  // 32 KB, [k][c] for this block's 64-col half

  const int tid = threadIdx.x;
  const int r0 = blockIdx.x * 64;
  const int c0 = blockIdx.y * 64;

  // stage weight half: 128x64 = 2048 float4 / 256 threads = 8 each
#pragma unroll
  for (int j = 0; j < 8; ++j) {
    int q = tid + 256 * j;
    int k = q >> 4, cq = (q & 15) * 4;
    float4 w = *(const float4*)(W + k * D + c0 + cq);
    *(float4*)&Ws[k * 64 + cq] = w;
  }
  // stage A rows, combining A1 + rowscale*A2
#pragma unroll
  for (int j = 0; j < 8; ++j) {
    int q = tid + 256 * j;
    int r = q >> 5, kq = (q & 31) * 4;
    int row = r0 + r;
    float4 v = make_float4(0.f, 0.f, 0.f, 0.f);
    if (row < n) {
      v = *(const float4*)(A1 + row * D + kq);
      if (HAS_A2) {
        float4 a2 = *(const float4*)(A2 + row * D + kq);
        float c = rowscale ? rowscale[row] : 1.0f;
        v.x = fmaf(c, a2.x, v.x);
        v.y = fmaf(c, a2.y, v.y);
        v.z = fmaf(c, a2.z, v.z);
        v.w = fmaf(c, a2.w, v.w);
      }
    }
    int col = (kq + 8 * (r & 3)) & (D - 1);
    *(float4*)&As[r * D + col] = v;
  }
  __syncthreads();

  const int ty = tid >> 4, tx = tid & 15;
  float acc[4][4] = {};
  const float* as0 = &As[(4 * ty + 0) * D];
  const float* as1 = &As[(4 * ty + 1) * D];
  const float* as2 = &As[(4 * ty + 2) * D];
  const float* as3 = &As[(4 * ty + 3) * D];
  const float* wsp = &Ws[tx * 4];

#pragma unroll
  for (int k = 0; k < D; ++k) {
    float a0 = as0[k];
    float a1 = as1[(k + 8) & (D - 1)];
    float a2 = as2[(k + 16) & (D - 1)];
    float a3 = as3[(k + 24) & (D - 1)];
    float4 w = *(const float4*)(wsp + k * 64);
    acc[0][0] = fmaf(a0, w.x, acc[0][0]);
    acc[0][1] = fmaf(a0, w.y, acc[0][1]);
    acc[0][2] = fmaf(a0, w.z, acc[0][2]);
    acc[0][3] = fmaf(a0, w.w, acc[0][3]);
    acc[1][0] = fmaf(a1, w.x, acc[1][0]);
    acc[1][1] = fmaf(a1, w.y, acc[1][1]);
    acc[1][2] = fmaf(a1, w.z, acc[1][2]);
    acc[1][3] = fmaf(a1, w.w, acc[1][3]);
    acc[2][0] = fmaf(a2, w.x, acc[2][0]);
    acc[2][1] = fmaf(a2, w.y, acc[2][1]);
    acc[2][2] = fmaf(a2, w.z, acc[2][2]);
    acc[2][3] = fmaf(a2, w.w, acc[2][3]);
    acc[3][0] = fmaf(a3, w.x, acc[3][0]);
    acc[3][1] = fmaf(a3, w.y, acc[3][1]);
    acc[3][2] = fmaf(a3, w.z, acc[3][2]);
    acc[3][3] = fmaf(a3, w.w, acc[3][3]);
  }

  float4 b = *(const float4*)(bias + c0 + tx * 4);
#pragma unroll
  for (int i = 0; i < 4; ++i) {
    int row = r0 + 4 * ty + i;
    if (row < n) {
      float* po = out + row * D + c0 + tx * 4;
      float4 o;
      o.x = fmaf(b.x, bscale, acc[i][0]);
      o.y = fmaf(b.y, bscale, acc[i][1]);
      o.z = fmaf(b.z, bscale, acc[i][2]);
      o.w = fmaf(b.w, bscale, acc[i][3]);
      if (ACCUM) {
        float4 p = *(const float4*)po;
        o.x += p.x; o.y += p.y; o.z += p.z; o.w += p.w;
      }
      if (RELU) {
        o.x = fmaxf(o.x, 0.f);
        o.y = fmaxf(o.y, 0.f);
        o.z = fmaxf(o.z, 0.f);
        o.w = fmaxf(o.w, 0.f);
      }
      *(float4*)po = o;
    }
  }
}

// ---------------------------------------------------------------------------
extern "C" void kernel_launch(void* const* d_in, const int* in_sizes, int n_in,
                              void* d_out, int out_size, void* d_ws, size_t ws_size,
                              hipStream_t stream) {
  const float* x   = (const float*)d_in[0];
  const int*   ei  = (const int*)d_in[1];
  const float* gw1 = (const float*)d_in[2];
  const float* gb1 = (const float*)d_in[3];
  const float* gw2 = (const float*)d_in[4];
  const float* gb2 = (const float*)d_in[5];
  const float* iw1 = (const float*)d_in[6];
  const float* ib1 = (const float*)d_in[7];
  const float* iw2 = (const float*)d_in[8];
  const float* ib2 = (const float*)d_in[9];
  const float* lw  = (const float*)d_in[10];
  const float* lb  = (const float*)d_in[11];
  const float* fw  = (const float*)d_in[12];
  const float* fb  = (const float*)d_in[13];
  float* out = (float*)d_out;

  const int n = in_sizes[0] / D;
  const int E = in_sizes[1] / 2;
  const int* src = ei;
  const int* dst = ei + E;

  float* ws = (float*)d_ws;
  const long ND = (long)n * D;
  float* deg   = ws;
  float* dinv  = ws + n;
  float* dinv2 = ws + 2 * n;
  float* buf1  = ws + 3 * n;       // passA: aggGin0  | passB: aggGcn1
  float* buf2  = buf1 + ND;        // passA: aggGcn0  | passB: aggGin1
  float* bufH  = buf1 + 2 * ND;    // h, later t
  float* bufG  = buf1 + 3 * ND;    // g

  hipMemsetAsync(deg, 0, n * sizeof(float), stream);
  hipMemsetAsync(buf1, 0, 2 * ND * sizeof(float), stream);

  deg_kernel<<<1024, 256, 0, stream>>>(dst, deg, E);
  dinv_kernel<<<(n + 255) / 256, 256, 0, stream>>>(deg, dinv, dinv2, n);

  passA_kernel<<<2048, 256, 0, stream>>>(x, dinv, src, dst, buf1, buf2, E);

  dim3 gg((n + 63) / 64, 2);
  // h = relu((aggGcn0 + dinv2*x) @ W1 + b1)
  gemm_kernel<true,  false, true ><<<gg, 256, 0, stream>>>(buf2, x, dinv2, gw1, gb1, 1.f, bufH, n);
  // g = (x + aggGin0) @ Wg1 + bg1
  gemm_kernel<false, false, true ><<<gg, 256, 0, stream>>>(x, buf1, nullptr, iw1, ib1, 1.f, bufG, n);

  hipMemsetAsync(buf1, 0, 2 * ND * sizeof(float), stream);
  passB_kernel<<<2048, 256, 0, stream>>>(bufH, bufG, dinv, src, dst, buf1, buf2, E);

  // s (in d_out) = (aggGcn1 + dinv2*h) @ W2 + b2
  gemm_kernel<false, false, true ><<<gg, 256, 0, stream>>>(buf1, bufH, dinv2, gw2, gb2, 1.f, out, n);
  // s += (g + aggGin1) @ Wg2 + bg2
  gemm_kernel<false, true,  true ><<<gg, 256, 0, stream>>>(bufG, buf2, nullptr, iw2, ib2, 1.f, out, n);
  // t (in bufH) = s @ lin_w + 2*lin_b
  gemm_kernel<false, false, false><<<gg, 256, 0, stream>>>(out, nullptr, nullptr, lw, lb, 2.f, bufH, n);
  // out = t @ fc_w + fc_b
  gemm_kernel<false, false, false><<<gg, 256, 0, stream>>>(bufH, nullptr, nullptr, fw, fb, 1.f, out, n);
}

// Round 2
// 986.463 us; speedup vs baseline: 15.9231x; 15.9231x over previous
//
#include <hip/hip_runtime.h>

#define D 128

// ---------------------------------------------------------------------------
// int degree histogram: ideg[dst] += 1 per edge
// ---------------------------------------------------------------------------
__global__ void ideg_kernel(const int* __restrict__ dst, int* __restrict__ ideg, int E) {
  int i = blockIdx.x * blockDim.x + threadIdx.x;
  int stride = gridDim.x * blockDim.x;
  for (int e = i; e < E; e += stride)
    atomicAdd(&ideg[dst[e]], 1);
}

// dinv = rsqrt(deg+1), dinv2 = dinv^2 (self-loop coefficient)
__global__ void dinv_kernel(const int* __restrict__ ideg, float* __restrict__ dinv,
                            float* __restrict__ dinv2, int n) {
  int i = blockIdx.x * blockDim.x + threadIdx.x;
  if (i < n) {
    float r = rsqrtf((float)ideg[i] + 1.0f);
    dinv[i] = r;
    dinv2[i] = r * r;
  }
}

// ---------------------------------------------------------------------------
// 3-kernel exclusive scan over ideg[n] -> rowptr[n+1]
// ---------------------------------------------------------------------------
__global__ void scan1_kernel(const int* __restrict__ deg, int* __restrict__ incl,
                             int* __restrict__ bsum, int n) {
  __shared__ int tmp[256];
  int t = threadIdx.x;
  int i = blockIdx.x * 256 + t;
  int v = (i < n) ? deg[i] : 0;
  tmp[t] = v;
  __syncthreads();
#pragma unroll
  for (int off = 1; off < 256; off <<= 1) {
    int u = (t >= off) ? tmp[t - off] : 0;
    __syncthreads();
    tmp[t] += u;
    __syncthreads();
  }
  if (i < n) incl[i] = tmp[t];
  if (t == 255) bsum[blockIdx.x] = tmp[255];
}

__global__ void scan2_kernel(int* __restrict__ bsum, int nb) {
  __shared__ int tmp[256];
  __shared__ int carry_s;
  int t = threadIdx.x;
  if (t == 0) carry_s = 0;
  __syncthreads();
  for (int base = 0; base < nb; base += 256) {
    int v = (base + t < nb) ? bsum[base + t] : 0;
    tmp[t] = v;
    __syncthreads();
#pragma unroll
    for (int off = 1; off < 256; off <<= 1) {
      int u = (t >= off) ? tmp[t - off] : 0;
      __syncthreads();
      tmp[t] += u;
      __syncthreads();
    }
    int inc = tmp[t] + carry_s;
    if (base + t < nb) bsum[base + t] = inc;
    __syncthreads();
    if (t == 255) carry_s = inc;
    __syncthreads();
  }
}

__global__ void scan3_kernel(const int* __restrict__ deg, const int* __restrict__ incl,
                             const int* __restrict__ bsum, int* __restrict__ rowptr,
                             int n, int nb, int E) {
  int i = blockIdx.x * 256 + threadIdx.x;
  if (i < n) {
    int carry = (blockIdx.x > 0) ? bsum[blockIdx.x - 1] : 0;
    rowptr[i] = incl[i] - deg[i] + carry;
  }
  if (i == 0) rowptr[n] = E;
}

// scatter edges into CSR slots: csrc[rowptr[d] + pos] = src[e]
__global__ void scatter_kernel(const int* __restrict__ src, const int* __restrict__ dst,
                               const int* __restrict__ rowptr, int* __restrict__ cursor,
                               int* __restrict__ csrc, int E) {
  int i = blockIdx.x * blockDim.x + threadIdx.x;
  int stride = gridDim.x * blockDim.x;
  for (int e = i; e < E; e += stride) {
    int d = dst[e];
    int pos = atomicAdd(&cursor[d], 1);
    csrc[rowptr[d] + pos] = src[e];
  }
}

// ---------------------------------------------------------------------------
// gather pass A: one wave per dst node, lane covers features 2l, 2l+1
//   gin[d] = sum_{s in N(d)} x[s]
//   gcn[d] = dinv[d] * sum_{s in N(d)} dinv[s]*x[s]
// ---------------------------------------------------------------------------
__global__ __launch_bounds__(256) void gatherA_kernel(
    const float* __restrict__ x, const float* __restrict__ dinv,
    const int* __restrict__ rowptr, const int* __restrict__ csrc,
    float* __restrict__ gin, float* __restrict__ gcn, int n) {
  int w = blockIdx.x * 4 + (threadIdx.x >> 6);
  if (w >= n) return;
  int lane = threadIdx.x & 63;
  int beg = rowptr[w], end = rowptr[w + 1];
  float2 sg = make_float2(0.f, 0.f), sc = make_float2(0.f, 0.f);
  int j = beg;
  for (; j + 1 < end; j += 2) {
    int s0 = csrc[j], s1 = csrc[j + 1];
    float w0 = dinv[s0], w1 = dinv[s1];
    float2 v0 = *(const float2*)(x + (long)s0 * D + 2 * lane);
    float2 v1 = *(const float2*)(x + (long)s1 * D + 2 * lane);
    sg.x += v0.x + v1.x;
    sg.y += v0.y + v1.y;
    sc.x = fmaf(w0, v0.x, fmaf(w1, v1.x, sc.x));
    sc.y = fmaf(w0, v0.y, fmaf(w1, v1.y, sc.y));
  }
  if (j < end) {
    int s0 = csrc[j];
    float w0 = dinv[s0];
    float2 v0 = *(const float2*)(x + (long)s0 * D + 2 * lane);
    sg.x += v0.x; sg.y += v0.y;
    sc.x = fmaf(w0, v0.x, sc.x);
    sc.y = fmaf(w0, v0.y, sc.y);
  }
  float dd = dinv[w];
  *(float2*)(gin + (long)w * D + 2 * lane) = sg;
  float2 o = make_float2(dd * sc.x, dd * sc.y);
  *(float2*)(gcn + (long)w * D + 2 * lane) = o;
}

// gather pass B: gcn1[d] = dinv[d]*sum dinv[s]*h[s];  gin1[d] = sum g[s]
__global__ __launch_bounds__(256) void gatherB_kernel(
    const float* __restrict__ h, const float* __restrict__ g,
    const float* __restrict__ dinv,
    const int* __restrict__ rowptr, const int* __restrict__ csrc,
    float* __restrict__ gcn, float* __restrict__ gin, int n) {
  int w = blockIdx.x * 4 + (threadIdx.x >> 6);
  if (w >= n) return;
  int lane = threadIdx.x & 63;
  int beg = rowptr[w], end = rowptr[w + 1];
  float2 sc = make_float2(0.f, 0.f), sg = make_float2(0.f, 0.f);
  int j = beg;
  for (; j + 1 < end; j += 2) {
    int s0 = csrc[j], s1 = csrc[j + 1];
    float w0 = dinv[s0], w1 = dinv[s1];
    float2 vh0 = *(const float2*)(h + (long)s0 * D + 2 * lane);
    float2 vh1 = *(const float2*)(h + (long)s1 * D + 2 * lane);
    float2 vg0 = *(const float2*)(g + (long)s0 * D + 2 * lane);
    float2 vg1 = *(const float2*)(g + (long)s1 * D + 2 * lane);
    sc.x = fmaf(w0, vh0.x, fmaf(w1, vh1.x, sc.x));
    sc.y = fmaf(w0, vh0.y, fmaf(w1, vh1.y, sc.y));
    sg.x += vg0.x + vg1.x;
    sg.y += vg0.y + vg1.y;
  }
  if (j < end) {
    int s0 = csrc[j];
    float w0 = dinv[s0];
    float2 vh0 = *(const float2*)(h + (long)s0 * D + 2 * lane);
    float2 vg0 = *(const float2*)(g + (long)s0 * D + 2 * lane);
    sc.x = fmaf(w0, vh0.x, sc.x);
    sc.y = fmaf(w0, vh0.y, sc.y);
    sg.x += vg0.x; sg.y += vg0.y;
  }
  float dd = dinv[w];
  float2 o = make_float2(dd * sc.x, dd * sc.y);
  *(float2*)(gcn + (long)w * D + 2 * lane) = o;
  *(float2*)(gin + (long)w * D + 2 * lane) = sg;
}

// ---------------------------------------------------------------------------
// GEMM: out[r][c] = f( (A1[r] + rowscale[r]*A2[r]) @ W + bscale*bias [+ out] )
// 64x64 block tile, 256 threads, 4x4 register tile. As padded +4 (2-way LDS
// conflicts only = free). Partial unroll to control register pressure.
// ---------------------------------------------------------------------------
#define LDA 132
template <bool RELU, bool ACCUM, bool HAS_A2>
__global__ __launch_bounds__(256) void gemm_kernel(
    const float* __restrict__ A1, const float* __restrict__ A2,
    const float* __restrict__ rowscale, const float* __restrict__ W,
    const float* __restrict__ bias, float bscale,
    float* __restrict__ out, int n) {
  __shared__ float As[64 * LDA];
  __shared__ float Ws[D * 64];

  const int tid = threadIdx.x;
  const int r0 = blockIdx.x * 64;
  const int c0 = blockIdx.y * 64;

#pragma unroll
  for (int j = 0; j < 8; ++j) {
    int q = tid + 256 * j;
    int k = q >> 4, cq = (q & 15) * 4;
    float4 w = *(const float4*)(W + k * D + c0 + cq);
    *(float4*)&Ws[k * 64 + cq] = w;
  }
#pragma unroll
  for (int j = 0; j < 8; ++j) {
    int q = tid + 256 * j;
    int r = q >> 5, kq = (q & 31) * 4;
    int row = r0 + r;
    float4 v = make_float4(0.f, 0.f, 0.f, 0.f);
    if (row < n) {
      v = *(const float4*)(A1 + (long)row * D + kq);
      if (HAS_A2) {
        float4 a2 = *(const float4*)(A2 + (long)row * D + kq);
        float c = rowscale ? rowscale[row] : 1.0f;
        v.x = fmaf(c, a2.x, v.x);
        v.y = fmaf(c, a2.y, v.y);
        v.z = fmaf(c, a2.z, v.z);
        v.w = fmaf(c, a2.w, v.w);
      }
    }
    *(float4*)&As[r * LDA + kq] = v;
  }
  __syncthreads();

  const int ty = tid >> 4, tx = tid & 15;
  float acc[4][4] = {};
  const float* as0 = &As[(4 * ty + 0) * LDA];
  const float* as1 = &As[(4 * ty + 1) * LDA];
  const float* as2 = &As[(4 * ty + 2) * LDA];
  const float* as3 = &As[(4 * ty + 3) * LDA];
  const float* wsp = &Ws[tx * 4];

#pragma unroll 16
  for (int k = 0; k < D; ++k) {
    float a0 = as0[k];
    float a1 = as1[k];
    float a2 = as2[k];
    float a3 = as3[k];
    float4 w = *(const float4*)(wsp + k * 64);
    acc[0][0] = fmaf(a0, w.x, acc[0][0]);
    acc[0][1] = fmaf(a0, w.y, acc[0][1]);
    acc[0][2] = fmaf(a0, w.z, acc[0][2]);
    acc[0][3] = fmaf(a0, w.w, acc[0][3]);
    acc[1][0] = fmaf(a1, w.x, acc[1][0]);
    acc[1][1] = fmaf(a1, w.y, acc[1][1]);
    acc[1][2] = fmaf(a1, w.z, acc[1][2]);
    acc[1][3] = fmaf(a1, w.w, acc[1][3]);
    acc[2][0] = fmaf(a2, w.x, acc[2][0]);
    acc[2][1] = fmaf(a2, w.y, acc[2][1]);
    acc[2][2] = fmaf(a2, w.z, acc[2][2]);
    acc[2][3] = fmaf(a2, w.w, acc[2][3]);
    acc[3][0] = fmaf(a3, w.x, acc[3][0]);
    acc[3][1] = fmaf(a3, w.y, acc[3][1]);
    acc[3][2] = fmaf(a3, w.z, acc[3][2]);
    acc[3][3] = fmaf(a3, w.w, acc[3][3]);
  }

  float4 b = *(const float4*)(bias + c0 + tx * 4);
#pragma unroll
  for (int i = 0; i < 4; ++i) {
    int row = r0 + 4 * ty + i;
    if (row < n) {
      float* po = out + (long)row * D + c0 + tx * 4;
      float4 o;
      o.x = fmaf(b.x, bscale, acc[i][0]);
      o.y = fmaf(b.y, bscale, acc[i][1]);
      o.z = fmaf(b.z, bscale, acc[i][2]);
      o.w = fmaf(b.w, bscale, acc[i][3]);
      if (ACCUM) {
        float4 p = *(const float4*)po;
        o.x += p.x; o.y += p.y; o.z += p.z; o.w += p.w;
      }
      if (RELU) {
        o.x = fmaxf(o.x, 0.f);
        o.y = fmaxf(o.y, 0.f);
        o.z = fmaxf(o.z, 0.f);
        o.w = fmaxf(o.w, 0.f);
      }
      *(float4*)po = o;
    }
  }
}

// ---------------------------------------------------------------------------
extern "C" void kernel_launch(void* const* d_in, const int* in_sizes, int n_in,
                              void* d_out, int out_size, void* d_ws, size_t ws_size,
                              hipStream_t stream) {
  const float* x   = (const float*)d_in[0];
  const int*   ei  = (const int*)d_in[1];
  const float* gw1 = (const float*)d_in[2];
  const float* gb1 = (const float*)d_in[3];
  const float* gw2 = (const float*)d_in[4];
  const float* gb2 = (const float*)d_in[5];
  const float* iw1 = (const float*)d_in[6];
  const float* ib1 = (const float*)d_in[7];
  const float* iw2 = (const float*)d_in[8];
  const float* ib2 = (const float*)d_in[9];
  const float* lw  = (const float*)d_in[10];
  const float* lb  = (const float*)d_in[11];
  const float* fw  = (const float*)d_in[12];
  const float* fb  = (const float*)d_in[13];
  float* out = (float*)d_out;

  const int n = in_sizes[0] / D;
  const int E = in_sizes[1] / 2;
  const int* src = ei;
  const int* dst = ei + E;
  const int nb = (n + 255) / 256;

  // ---- workspace layout ----
  char* p = (char*)d_ws;
  int* ideg   = (int*)p;            p += (size_t)n * 4;
  int* incl   = (int*)p;            p += (size_t)n * 4;
  int* rowptr = (int*)p;            p += (size_t)(n + 1) * 4;
  int* bsum   = (int*)p;            p += 1024 * 4;
  int* cursor = (int*)p;            p += (size_t)n * 4;
  int* csrc   = (int*)p;            p += (size_t)E * 4;
  float* dinv  = (float*)p;         p += (size_t)n * 4;
  float* dinv2 = (float*)p;         p += (size_t)n * 4;
  const long ND = (long)n * D;
  float* buf1 = (float*)p;          p += ND * 4;
  float* buf2 = (float*)p;          p += ND * 4;
  float* bufH = (float*)p;          p += ND * 4;
  float* bufG = (float*)p;          p += ND * 4;

  hipMemsetAsync(ideg, 0, (size_t)n * 4, stream);
  hipMemsetAsync(cursor, 0, (size_t)n * 4, stream);

  ideg_kernel<<<2048, 256, 0, stream>>>(dst, ideg, E);
  dinv_kernel<<<nb, 256, 0, stream>>>(ideg, dinv, dinv2, n);
  scan1_kernel<<<nb, 256, 0, stream>>>(ideg, incl, bsum, n);
  scan2_kernel<<<1, 256, 0, stream>>>(bsum, nb);
  scan3_kernel<<<nb, 256, 0, stream>>>(ideg, incl, bsum, rowptr, n, nb, E);
  scatter_kernel<<<2048, 256, 0, stream>>>(src, dst, rowptr, cursor, csrc, E);

  gatherA_kernel<<<(n + 3) / 4, 256, 0, stream>>>(x, dinv, rowptr, csrc, buf1, buf2, n);

  dim3 gg((n + 63) / 64, 2);
  // h = relu((aggGcn0 + dinv2*x) @ W1 + b1)
  gemm_kernel<true,  false, true ><<<gg, 256, 0, stream>>>(buf2, x, dinv2, gw1, gb1, 1.f, bufH, n);
  // g = (x + aggGin0) @ Wg1 + bg1
  gemm_kernel<false, false, true ><<<gg, 256, 0, stream>>>(x, buf1, nullptr, iw1, ib1, 1.f, bufG, n);

  gatherB_kernel<<<(n + 3) / 4, 256, 0, stream>>>(bufH, bufG, dinv, rowptr, csrc, buf1, buf2, n);

  // s (in d_out) = (aggGcn1 + dinv2*h) @ W2 + b2
  gemm_kernel<false, false, true ><<<gg, 256, 0, stream>>>(buf1, bufH, dinv2, gw2, gb2, 1.f, out, n);
  // s += (g + aggGin1) @ Wg2 + bg2
  gemm_kernel<false, true,  true ><<<gg, 256, 0, stream>>>(bufG, buf2, nullptr, iw2, ib2, 1.f, out, n);
  // t (in bufH) = s @ lin_w + 2*lin_b
  gemm_kernel<false, false, false><<<gg, 256, 0, stream>>>(out, nullptr, nullptr, lw, lb, 2.f, bufH, n);
  // out = t @ fc_w + fc_b
  gemm_kernel<false, false, false><<<gg, 256, 0, stream>>>(bufH, nullptr, nullptr, fw, fb, 1.f, out, n);
}

// Round 3
// 536.710 us; speedup vs baseline: 29.2663x; 1.8380x over previous
//
#include <hip/hip_runtime.h>

#define D 128

using s8v = __attribute__((ext_vector_type(8))) short;
using f4v = __attribute__((ext_vector_type(4))) float;

__device__ __forceinline__ float bf2f(ushort u) {
  union { uint i; float f; } v; v.i = ((uint)u) << 16; return v.f;
}
__device__ __forceinline__ ushort f2bf(float f) {
  union { float f; uint i; } v; v.f = f;
  uint b = v.i;
  return (ushort)((b + 0x7fffu + ((b >> 16) & 1u)) >> 16);
}

// ---------------------------------------------------------------------------
// CSR build
// ---------------------------------------------------------------------------
__global__ void ideg_kernel(const int* __restrict__ dst, int* __restrict__ ideg, int E) {
  int i = blockIdx.x * blockDim.x + threadIdx.x;
  int stride = gridDim.x * blockDim.x;
  for (int e = i; e < E; e += stride)
    atomicAdd(&ideg[dst[e]], 1);
}

__global__ void dinv_kernel(const int* __restrict__ ideg, float* __restrict__ dinv, int n) {
  int i = blockIdx.x * blockDim.x + threadIdx.x;
  if (i < n) dinv[i] = rsqrtf((float)ideg[i] + 1.0f);
}

__global__ void scan1_kernel(const int* __restrict__ deg, int* __restrict__ incl,
                             int* __restrict__ bsum, int n) {
  __shared__ int tmp[256];
  int t = threadIdx.x;
  int i = blockIdx.x * 256 + t;
  int v = (i < n) ? deg[i] : 0;
  tmp[t] = v;
  __syncthreads();
#pragma unroll
  for (int off = 1; off < 256; off <<= 1) {
    int u = (t >= off) ? tmp[t - off] : 0;
    __syncthreads();
    tmp[t] += u;
    __syncthreads();
  }
  if (i < n) incl[i] = tmp[t];
  if (t == 255) bsum[blockIdx.x] = tmp[255];
}

__global__ void scan2_kernel(int* __restrict__ bsum, int nb) {
  __shared__ int tmp[256];
  __shared__ int carry_s;
  int t = threadIdx.x;
  if (t == 0) carry_s = 0;
  __syncthreads();
  for (int base = 0; base < nb; base += 256) {
    int v = (base + t < nb) ? bsum[base + t] : 0;
    tmp[t] = v;
    __syncthreads();
#pragma unroll
    for (int off = 1; off < 256; off <<= 1) {
      int u = (t >= off) ? tmp[t - off] : 0;
      __syncthreads();
      tmp[t] += u;
      __syncthreads();
    }
    int inc = tmp[t] + carry_s;
    if (base + t < nb) bsum[base + t] = inc;
    __syncthreads();
    if (t == 255) carry_s = inc;
    __syncthreads();
  }
}

__global__ void scan3_kernel(const int* __restrict__ deg, const int* __restrict__ incl,
                             const int* __restrict__ bsum, int* __restrict__ rowptr,
                             int n, int nb, int E) {
  int i = blockIdx.x * 256 + threadIdx.x;
  if (i < n) {
    int carry = (blockIdx.x > 0) ? bsum[blockIdx.x - 1] : 0;
    rowptr[i] = incl[i] - deg[i] + carry;
  }
  if (i == 0) rowptr[n] = E;
}

__global__ void scatter_kernel(const int* __restrict__ src, const int* __restrict__ dst,
                               const int* __restrict__ rowptr, int* __restrict__ cursor,
                               int* __restrict__ csrc, int E) {
  int i = blockIdx.x * blockDim.x + threadIdx.x;
  int stride = gridDim.x * blockDim.x;
  for (int e = i; e < E; e += stride) {
    int d = dst[e];
    int pos = atomicAdd(&cursor[d], 1);
    csrc[rowptr[d] + pos] = src[e];
  }
}

// ---------------------------------------------------------------------------
// x (f32) -> xb (bf16)
// ---------------------------------------------------------------------------
__global__ void xcvt_kernel(const float* __restrict__ x, ushort* __restrict__ xb, long total) {
  long i = (long)blockIdx.x * blockDim.x + threadIdx.x;
  long stride = (long)gridDim.x * blockDim.x;
  for (long t = i * 4; t < total; t += stride * 4) {
    float4 v = *(const float4*)(x + t);
    ushort4 u;
    u.x = f2bf(v.x); u.y = f2bf(v.y); u.z = f2bf(v.z); u.w = f2bf(v.w);
    *(ushort4*)(xb + t) = u;
  }
}

// transpose+convert two 128x128 f32 weights to bf16 [col][k]
__global__ void wtrans_kernel(const float* __restrict__ w1, const float* __restrict__ w2,
                              ushort* __restrict__ o1, ushort* __restrict__ o2) {
  int t = blockIdx.x * 256 + threadIdx.x;  // grid 128 blocks -> 32768 threads
  int which = t >> 14;
  int q = t & 16383;
  int k = q >> 7, c = q & 127;
  const float* w = which ? w2 : w1;
  ushort* o = which ? o2 : o1;
  o[c * 128 + k] = f2bf(w[k * 128 + c]);
}

// C = A @ B, all f32 128x128 (tiny)
__global__ void mm128_kernel(const float* __restrict__ A, const float* __restrict__ B,
                             float* __restrict__ C) {
  int t = blockIdx.x * 256 + threadIdx.x;  // grid 64
  int r = t >> 7, c = t & 127;
  float s = 0.f;
#pragma unroll 8
  for (int k = 0; k < 128; ++k) s = fmaf(A[r * 128 + k], B[k * 128 + c], s);
  C[r * 128 + c] = s;
}

// Oa = bf16T(W2a @ LF), Ob = bf16T(W2b @ LF)
__global__ void foldw_kernel(const float* __restrict__ W2a, const float* __restrict__ W2b,
                             const float* __restrict__ LF,
                             ushort* __restrict__ Oa, ushort* __restrict__ Ob) {
  int t = blockIdx.x * 256 + threadIdx.x;  // grid 128
  int which = t >> 14;
  int q = t & 16383;
  int k = q >> 7, c = q & 127;
  const float* W = which ? W2b : W2a;
  ushort* O = which ? Ob : Oa;
  float s = 0.f;
#pragma unroll 8
  for (int j = 0; j < 128; ++j) s = fmaf(W[k * 128 + j], LF[j * 128 + c], s);
  O[c * 128 + k] = f2bf(s);
}

// btot[c] = (gb2+ib2) @ LF + 2*lb @ fw + fb
__global__ void foldb_kernel(const float* __restrict__ gb2, const float* __restrict__ ib2,
                             const float* __restrict__ LF, const float* __restrict__ lb,
                             const float* __restrict__ fw, const float* __restrict__ fb,
                             float* __restrict__ btot) {
  int c = threadIdx.x;
  if (c < 128) {
    float s = fb[c];
#pragma unroll 8
    for (int j = 0; j < 128; ++j) {
      s = fmaf(gb2[j] + ib2[j], LF[j * 128 + c], s);
      s = fmaf(2.f * lb[j], fw[j * 128 + c], s);
    }
    btot[c] = s;
  }
}

// ---------------------------------------------------------------------------
// gather A: per dst node w (one wave), lane covers features 2l,2l+1
//   Agin[w] = x[w] + sum x[s]         (bf16 out)
//   Agcn[w] = dinv[w]*(sum dinv[s]x[s] + dinv[w]*x[w])
// ---------------------------------------------------------------------------
__global__ __launch_bounds__(256) void gatherA_kernel(
    const ushort* __restrict__ xb, const float* __restrict__ dinv,
    const int* __restrict__ rowptr, const int* __restrict__ csrc,
    ushort* __restrict__ Agcn, ushort* __restrict__ Agin, int n) {
  int w = blockIdx.x * 4 + (threadIdx.x >> 6);
  if (w >= n) return;
  int lane = threadIdx.x & 63;
  int beg = rowptr[w], end = rowptr[w + 1];
  float2 sg = make_float2(0.f, 0.f), sc = make_float2(0.f, 0.f);
  int j = beg;
  for (; j + 1 < end; j += 2) {
    int s0 = csrc[j], s1 = csrc[j + 1];
    float w0 = dinv[s0], w1 = dinv[s1];
    ushort2 u0 = *(const ushort2*)(xb + (long)s0 * D + 2 * lane);
    ushort2 u1 = *(const ushort2*)(xb + (long)s1 * D + 2 * lane);
    float a0 = bf2f(u0.x), b0 = bf2f(u0.y);
    float a1 = bf2f(u1.x), b1 = bf2f(u1.y);
    sg.x += a0 + a1;
    sg.y += b0 + b1;
    sc.x = fmaf(w0, a0, fmaf(w1, a1, sc.x));
    sc.y = fmaf(w0, b0, fmaf(w1, b1, sc.y));
  }
  if (j < end) {
    int s0 = csrc[j];
    float w0 = dinv[s0];
    ushort2 u0 = *(const ushort2*)(xb + (long)s0 * D + 2 * lane);
    float a0 = bf2f(u0.x), b0 = bf2f(u0.y);
    sg.x += a0; sg.y += b0;
    sc.x = fmaf(w0, a0, sc.x);
    sc.y = fmaf(w0, b0, sc.y);
  }
  ushort2 us = *(const ushort2*)(xb + (long)w * D + 2 * lane);
  float xs = bf2f(us.x), ys = bf2f(us.y);
  float dd = dinv[w];
  ushort2 og, oc;
  og.x = f2bf(xs + sg.x);
  og.y = f2bf(ys + sg.y);
  oc.x = f2bf(dd * (sc.x + dd * xs));
  oc.y = f2bf(dd * (sc.y + dd * ys));
  *(ushort2*)(Agin + (long)w * D + 2 * lane) = og;
  *(ushort2*)(Agcn + (long)w * D + 2 * lane) = oc;
}

// gather B: Agcn2[w] = dinv[w]*(sum dinv[s]h[s] + dinv[w]*h[w]);  Agin2[w] = g[w] + sum g[s]
__global__ __launch_bounds__(256) void gatherB_kernel(
    const ushort* __restrict__ hb, const ushort* __restrict__ gb,
    const float* __restrict__ dinv,
    const int* __restrict__ rowptr, const int* __restrict__ csrc,
    ushort* __restrict__ Agcn, ushort* __restrict__ Agin, int n) {
  int w = blockIdx.x * 4 + (threadIdx.x >> 6);
  if (w >= n) return;
  int lane = threadIdx.x & 63;
  int beg = rowptr[w], end = rowptr[w + 1];
  float2 sc = make_float2(0.f, 0.f), sg = make_float2(0.f, 0.f);
  int j = beg;
  for (; j + 1 < end; j += 2) {
    int s0 = csrc[j], s1 = csrc[j + 1];
    float w0 = dinv[s0], w1 = dinv[s1];
    ushort2 h0 = *(const ushort2*)(hb + (long)s0 * D + 2 * lane);
    ushort2 h1 = *(const ushort2*)(hb + (long)s1 * D + 2 * lane);
    ushort2 g0 = *(const ushort2*)(gb + (long)s0 * D + 2 * lane);
    ushort2 g1 = *(const ushort2*)(gb + (long)s1 * D + 2 * lane);
    sc.x = fmaf(w0, bf2f(h0.x), fmaf(w1, bf2f(h1.x), sc.x));
    sc.y = fmaf(w0, bf2f(h0.y), fmaf(w1, bf2f(h1.y), sc.y));
    sg.x += bf2f(g0.x) + bf2f(g1.x);
    sg.y += bf2f(g0.y) + bf2f(g1.y);
  }
  if (j < end) {
    int s0 = csrc[j];
    float w0 = dinv[s0];
    ushort2 h0 = *(const ushort2*)(hb + (long)s0 * D + 2 * lane);
    ushort2 g0 = *(const ushort2*)(gb + (long)s0 * D + 2 * lane);
    sc.x = fmaf(w0, bf2f(h0.x), sc.x);
    sc.y = fmaf(w0, bf2f(h0.y), sc.y);
    sg.x += bf2f(g0.x);
    sg.y += bf2f(g0.y);
  }
  ushort2 uh = *(const ushort2*)(hb + (long)w * D + 2 * lane);
  ushort2 ug = *(const ushort2*)(gb + (long)w * D + 2 * lane);
  float dd = dinv[w];
  ushort2 oc, og;
  oc.x = f2bf(dd * (sc.x + dd * bf2f(uh.x)));
  oc.y = f2bf(dd * (sc.y + dd * bf2f(uh.y)));
  og.x = f2bf(bf2f(ug.x) + sg.x);
  og.y = f2bf(bf2f(ug.y) + sg.y);
  *(ushort2*)(Agcn + (long)w * D + 2 * lane) = oc;
  *(ushort2*)(Agin + (long)w * D + 2 * lane) = og;
}

// ---------------------------------------------------------------------------
// MFMA GEMM: out = act(A @ WtT + bias), A [n][128] bf16, Wt [col][k] bf16.
// Block: 256 thr = 4 waves, 128 rows (32/wave, two 16-row tiles).
// W staged in LDS with 16B-chunk XOR swizzle (kc ^ (c&7)); A frags loaded
// straight from global (each byte read exactly once per kernel).
// DUAL: out = A1@Wt1T + A2@Wt2T + bias (shared accumulators).
// ---------------------------------------------------------------------------
template <bool RELU, bool OUT_BF16, bool DUAL>
__global__ __launch_bounds__(256) void mfma_gemm_kernel(
    const ushort* __restrict__ A1g, const ushort* __restrict__ A2g,
    const ushort* __restrict__ Wt1, const ushort* __restrict__ Wt2,
    const float* __restrict__ bias, void* __restrict__ outv, int n) {
  __shared__ ushort Ws[(DUAL ? 2 : 1) * 128 * 128];
  const int tid = threadIdx.x;
  const int wave = tid >> 6, lane = tid & 63;
  const int rlo = lane & 15, khi = lane >> 4;
  const int rb = blockIdx.x * 128 + wave * 32;

  // A fragments straight from global (issue first)
  s8v a1[2][4], a2[2][4];
#pragma unroll
  for (int rt = 0; rt < 2; ++rt) {
    int row = rb + rt * 16 + rlo;
    row = row < n ? row : n - 1;
    const ushort* p = A1g + (long)row * D + khi * 8;
#pragma unroll
    for (int ks = 0; ks < 4; ++ks) a1[rt][ks] = *(const s8v*)(p + ks * 32);
    if (DUAL) {
      const ushort* p2 = A2g + (long)row * D + khi * 8;
#pragma unroll
      for (int ks = 0; ks < 4; ++ks) a2[rt][ks] = *(const s8v*)(p2 + ks * 32);
    }
  }

  // stage weights to LDS (swizzled)
#pragma unroll
  for (int j = 0; j < 8; ++j) {
    int q = tid + 256 * j;
    int c = q >> 4, kc = q & 15;
    *(s8v*)&Ws[c * 128 + ((kc ^ (c & 7)) << 3)] = *(const s8v*)(Wt1 + c * 128 + kc * 8);
  }
  if (DUAL) {
#pragma unroll
    for (int j = 0; j < 8; ++j) {
      int q = tid + 256 * j;
      int c = q >> 4, kc = q & 15;
      *(s8v*)&Ws[128 * 128 + c * 128 + ((kc ^ (c & 7)) << 3)] =
          *(const s8v*)(Wt2 + c * 128 + kc * 8);
    }
  }
  __syncthreads();

  f4v acc[2][8];
#pragma unroll
  for (int rt = 0; rt < 2; ++rt)
#pragma unroll
    for (int ct = 0; ct < 8; ++ct) acc[rt][ct] = (f4v){0.f, 0.f, 0.f, 0.f};

  const int c_ = rlo;  // lane's column-within-tile
#pragma unroll
  for (int ks = 0; ks < 4; ++ks) {
#pragma unroll
    for (int ct = 0; ct < 8; ++ct) {
      int c = ct * 16 + c_;
      int kc = ks * 4 + khi;
      s8v b = *(const s8v*)&Ws[c * 128 + ((kc ^ (c & 7)) << 3)];
      acc[0][ct] = __builtin_amdgcn_mfma_f32_16x16x32_bf16(a1[0][ks], b, acc[0][ct], 0, 0, 0);
      acc[1][ct] = __builtin_amdgcn_mfma_f32_16x16x32_bf16(a1[1][ks], b, acc[1][ct], 0, 0, 0);
    }
  }
  if (DUAL) {
#pragma unroll
    for (int ks = 0; ks < 4; ++ks) {
#pragma unroll
      for (int ct = 0; ct < 8; ++ct) {
        int c = ct * 16 + c_;
        int kc = ks * 4 + khi;
        s8v b = *(const s8v*)&Ws[128 * 128 + c * 128 + ((kc ^ (c & 7)) << 3)];
        acc[0][ct] = __builtin_amdgcn_mfma_f32_16x16x32_bf16(a2[0][ks], b, acc[0][ct], 0, 0, 0);
        acc[1][ct] = __builtin_amdgcn_mfma_f32_16x16x32_bf16(a2[1][ks], b, acc[1][ct], 0, 0, 0);
      }
    }
  }

  // epilogue: C layout col = lane&15, row = 4*(lane>>4)+i
#pragma unroll
  for (int ct = 0; ct < 8; ++ct) {
    int col = ct * 16 + rlo;
    float bb = bias[col];
#pragma unroll
    for (int rt = 0; rt < 2; ++rt) {
#pragma unroll
      for (int i = 0; i < 4; ++i) {
        int row = rb + rt * 16 + 4 * khi + i;
        if (row < n) {
          float v = acc[rt][ct][i] + bb;
          if (RELU) v = fmaxf(v, 0.f);
          if (OUT_BF16)
            ((ushort*)outv)[(long)row * D + col] = f2bf(v);
          else
            ((float*)outv)[(long)row * D + col] = v;
        }
      }
    }
  }
}

// ---------------------------------------------------------------------------
extern "C" void kernel_launch(void* const* d_in, const int* in_sizes, int n_in,
                              void* d_out, int out_size, void* d_ws, size_t ws_size,
                              hipStream_t stream) {
  const float* x   = (const float*)d_in[0];
  const int*   ei  = (const int*)d_in[1];
  const float* gw1 = (const float*)d_in[2];
  const float* gb1 = (const float*)d_in[3];
  const float* gw2 = (const float*)d_in[4];
  const float* gb2 = (const float*)d_in[5];
  const float* iw1 = (const float*)d_in[6];
  const float* ib1 = (const float*)d_in[7];
  const float* iw2 = (const float*)d_in[8];
  const float* ib2 = (const float*)d_in[9];
  const float* lw  = (const float*)d_in[10];
  const float* lb  = (const float*)d_in[11];
  const float* fw  = (const float*)d_in[12];
  const float* fb  = (const float*)d_in[13];
  float* out = (float*)d_out;

  const int n = in_sizes[0] / D;
  const int E = in_sizes[1] / 2;
  const int* src = ei;
  const int* dst = ei + E;
  const int nb = (n + 255) / 256;
  const long ND = (long)n * D;

  char* p = (char*)d_ws;
  auto alloc = [&](size_t bytes) {
    char* r = p;
    p += (bytes + 255) & ~(size_t)255;
    return r;
  };
  int* ideg    = (int*)alloc((size_t)n * 4);
  int* incl    = (int*)alloc((size_t)n * 4);
  int* rowptr  = (int*)alloc((size_t)(n + 1) * 4);
  int* bsum    = (int*)alloc(1024 * 4);
  int* cursor  = (int*)alloc((size_t)n * 4);
  int* csrc    = (int*)alloc((size_t)E * 4);
  float* dinv  = (float*)alloc((size_t)n * 4);
  float* LF    = (float*)alloc(16384 * 4);
  float* btot  = (float*)alloc(128 * 4);
  ushort* xb   = (ushort*)alloc(ND * 2);
  ushort* Wt1g = (ushort*)alloc(16384 * 2);
  ushort* Wt1i = (ushort*)alloc(16384 * 2);
  ushort* Wt2g = (ushort*)alloc(16384 * 2);
  ushort* Wt2i = (ushort*)alloc(16384 * 2);
  ushort* Agcn = (ushort*)alloc(ND * 2);
  ushort* Agin = (ushort*)alloc(ND * 2);
  ushort* hbuf = (ushort*)alloc(ND * 2);
  ushort* gbuf = (ushort*)alloc(ND * 2);

  hipMemsetAsync(ideg, 0, (size_t)n * 4, stream);
  hipMemsetAsync(cursor, 0, (size_t)n * 4, stream);

  // CSR build + degree norm
  ideg_kernel<<<2048, 256, 0, stream>>>(dst, ideg, E);
  dinv_kernel<<<nb, 256, 0, stream>>>(ideg, dinv, n);
  scan1_kernel<<<nb, 256, 0, stream>>>(ideg, incl, bsum, n);
  scan2_kernel<<<1, 256, 0, stream>>>(bsum, nb);
  scan3_kernel<<<nb, 256, 0, stream>>>(ideg, incl, bsum, rowptr, n, nb, E);
  scatter_kernel<<<2048, 256, 0, stream>>>(src, dst, rowptr, cursor, csrc, E);

  // conversions + weight folds (independent of graph)
  xcvt_kernel<<<2048, 256, 0, stream>>>(x, xb, ND);
  wtrans_kernel<<<128, 256, 0, stream>>>(gw1, iw1, Wt1g, Wt1i);
  mm128_kernel<<<64, 256, 0, stream>>>(lw, fw, LF);
  foldw_kernel<<<128, 256, 0, stream>>>(gw2, iw2, LF, Wt2g, Wt2i);
  foldb_kernel<<<1, 128, 0, stream>>>(gb2, ib2, LF, lb, fw, fb, btot);

  // layer 1
  gatherA_kernel<<<(n + 3) / 4, 256, 0, stream>>>(xb, dinv, rowptr, csrc, Agcn, Agin, n);
  const int nblk = (n + 127) / 128;
  mfma_gemm_kernel<true,  true,  false><<<nblk, 256, 0, stream>>>(Agcn, nullptr, Wt1g, nullptr, gb1, hbuf, n);
  mfma_gemm_kernel<false, true,  false><<<nblk, 256, 0, stream>>>(Agin, nullptr, Wt1i, nullptr, ib1, gbuf, n);

  // layer 2 + folded linear tail
  gatherB_kernel<<<(n + 3) / 4, 256, 0, stream>>>(hbuf, gbuf, dinv, rowptr, csrc, Agcn, Agin, n);
  mfma_gemm_kernel<false, false, true ><<<nblk, 256, 0, stream>>>(Agcn, Agin, Wt2g, Wt2i, btot, out, n);
}

// Round 4
// 466.344 us; speedup vs baseline: 33.6823x; 1.1509x over previous
//
#include <hip/hip_runtime.h>

#define D 128

using s8v = __attribute__((ext_vector_type(8))) short;
using f4v = __attribute__((ext_vector_type(4))) float;

__device__ __forceinline__ float bf2f(ushort u) {
  union { uint i; float f; } v; v.i = ((uint)u) << 16; return v.f;
}
__device__ __forceinline__ ushort f2bf(float f) {
  union { float f; uint i; } v; v.f = f;
  uint b = v.i;
  return (ushort)((b + 0x7fffu + ((b >> 16) & 1u)) >> 16);
}

// ---------------------------------------------------------------------------
// degree histogram + per-edge slot: pos[e] = old count of dst[e]
// ---------------------------------------------------------------------------
__global__ void degpos_kernel(const int* __restrict__ dst, int* __restrict__ ideg,
                              int* __restrict__ pos, int E) {
  int i = blockIdx.x * blockDim.x + threadIdx.x;
  int stride = gridDim.x * blockDim.x;
  for (int e = i; e < E; e += stride)
    pos[e] = atomicAdd(&ideg[dst[e]], 1);
}

// ---------------------------------------------------------------------------
// 3-kernel exclusive scan over ideg[n] -> rowptr[n+1]; scan3 also emits dinv
// ---------------------------------------------------------------------------
__global__ void scan1_kernel(const int* __restrict__ deg, int* __restrict__ incl,
                             int* __restrict__ bsum, int n) {
  __shared__ int tmp[256];
  int t = threadIdx.x;
  int i = blockIdx.x * 256 + t;
  int v = (i < n) ? deg[i] : 0;
  tmp[t] = v;
  __syncthreads();
#pragma unroll
  for (int off = 1; off < 256; off <<= 1) {
    int u = (t >= off) ? tmp[t - off] : 0;
    __syncthreads();
    tmp[t] += u;
    __syncthreads();
  }
  if (i < n) incl[i] = tmp[t];
  if (t == 255) bsum[blockIdx.x] = tmp[255];
}

__global__ void scan2_kernel(int* __restrict__ bsum, int nb) {
  __shared__ int tmp[256];
  __shared__ int carry_s;
  int t = threadIdx.x;
  if (t == 0) carry_s = 0;
  __syncthreads();
  for (int base = 0; base < nb; base += 256) {
    int v = (base + t < nb) ? bsum[base + t] : 0;
    tmp[t] = v;
    __syncthreads();
#pragma unroll
    for (int off = 1; off < 256; off <<= 1) {
      int u = (t >= off) ? tmp[t - off] : 0;
      __syncthreads();
      tmp[t] += u;
      __syncthreads();
    }
    int inc = tmp[t] + carry_s;
    if (base + t < nb) bsum[base + t] = inc;
    __syncthreads();
    if (t == 255) carry_s = inc;
    __syncthreads();
  }
}

__global__ void scan3_kernel(const int* __restrict__ deg, const int* __restrict__ incl,
                             const int* __restrict__ bsum, int* __restrict__ rowptr,
                             float* __restrict__ dinv, int n, int E) {
  int i = blockIdx.x * 256 + threadIdx.x;
  if (i < n) {
    int carry = (blockIdx.x > 0) ? bsum[blockIdx.x - 1] : 0;
    int d = deg[i];
    rowptr[i] = incl[i] - d + carry;
    dinv[i] = rsqrtf((float)d + 1.0f);
  }
  if (i == 0) rowptr[n] = E;
}

// scatter (no atomics): csrc[rowptr[d] + pos[e]] = src[e]
__global__ void scatter_kernel(const int* __restrict__ src, const int* __restrict__ dst,
                               const int* __restrict__ rowptr, const int* __restrict__ pos,
                               int* __restrict__ csrc, int E) {
  int i = blockIdx.x * blockDim.x + threadIdx.x;
  int stride = gridDim.x * blockDim.x;
  for (int e = i; e < E; e += stride)
    csrc[rowptr[dst[e]] + pos[e]] = src[e];
}

// ---------------------------------------------------------------------------
// x (f32) -> xb (bf16), 8 elems/thread
// ---------------------------------------------------------------------------
__global__ void xcvt_kernel(const float* __restrict__ x, ushort* __restrict__ xb, long total) {
  long i = ((long)blockIdx.x * blockDim.x + threadIdx.x) * 8;
  long stride = (long)gridDim.x * blockDim.x * 8;
  for (long t = i; t < total; t += stride) {
    float4 v0 = *(const float4*)(x + t);
    float4 v1 = *(const float4*)(x + t + 4);
    s8v u;
    u[0] = (short)f2bf(v0.x); u[1] = (short)f2bf(v0.y);
    u[2] = (short)f2bf(v0.z); u[3] = (short)f2bf(v0.w);
    u[4] = (short)f2bf(v1.x); u[5] = (short)f2bf(v1.y);
    u[6] = (short)f2bf(v1.z); u[7] = (short)f2bf(v1.w);
    *(s8v*)(xb + t) = u;
  }
}

// prep1: blocks 0-127 transpose gw1/iw1 to bf16 [c][k]; blocks 128-191: LF = lw@fw
__global__ void prep1_kernel(const float* __restrict__ gw1, const float* __restrict__ iw1,
                             ushort* __restrict__ Wt1g, ushort* __restrict__ Wt1i,
                             const float* __restrict__ lw, const float* __restrict__ fw,
                             float* __restrict__ LF) {
  int b = blockIdx.x;
  if (b < 128) {
    int t = b * 256 + threadIdx.x;
    int which = t >> 14, q = t & 16383;
    int k = q >> 7, c = q & 127;
    const float* w = which ? iw1 : gw1;
    ushort* o = which ? Wt1i : Wt1g;
    o[c * 128 + k] = f2bf(w[k * 128 + c]);
  } else {
    int t = (b - 128) * 256 + threadIdx.x;
    int r = t >> 7, c = t & 127;
    float s = 0.f;
#pragma unroll 8
    for (int k = 0; k < 128; ++k) s = fmaf(lw[r * 128 + k], fw[k * 128 + c], s);
    LF[r * 128 + c] = s;
  }
}

// prep2: blocks 0-127: WtT2{g,i} = bf16T(w2@LF); block 128: folded bias
__global__ void prep2_kernel(const float* __restrict__ gw2, const float* __restrict__ iw2,
                             const float* __restrict__ LF,
                             ushort* __restrict__ Wt2g, ushort* __restrict__ Wt2i,
                             const float* __restrict__ gb2, const float* __restrict__ ib2,
                             const float* __restrict__ lb, const float* __restrict__ fw,
                             const float* __restrict__ fb, float* __restrict__ btot) {
  int b = blockIdx.x;
  if (b < 128) {
    int t = b * 256 + threadIdx.x;
    int which = t >> 14, q = t & 16383;
    int k = q >> 7, c = q & 127;
    const float* W = which ? iw2 : gw2;
    ushort* O = which ? Wt2i : Wt2g;
    float s = 0.f;
#pragma unroll 8
    for (int j = 0; j < 128; ++j) s = fmaf(W[k * 128 + j], LF[j * 128 + c], s);
    O[c * 128 + k] = f2bf(s);
  } else if (threadIdx.x < 128) {
    int c = threadIdx.x;
    float s = fb[c];
#pragma unroll 8
    for (int j = 0; j < 128; ++j) {
      s = fmaf(gb2[j] + ib2[j], LF[j * 128 + c], s);
      s = fmaf(2.f * lb[j], fw[j * 128 + c], s);
    }
    btot[c] = s;
  }
}

// ---------------------------------------------------------------------------
// gather A: per dst node (one wave), lane covers features 2l,2l+1.
// Writes interleaved A-matrix ab[node][256] = [gcn(128) | gin(128)] bf16.
// ---------------------------------------------------------------------------
__global__ __launch_bounds__(256) void gatherA_kernel(
    const ushort* __restrict__ xb, const float* __restrict__ dinv,
    const int* __restrict__ rowptr, const int* __restrict__ csrc,
    ushort* __restrict__ ab, int n) {
  int nd = blockIdx.x * 4 + (threadIdx.x >> 6);
  if (nd >= n) return;
  int lane = threadIdx.x & 63;
  int beg = rowptr[nd], end = rowptr[nd + 1];
  float2 sg = make_float2(0.f, 0.f), sc = make_float2(0.f, 0.f);
  int j = beg;
  for (; j + 1 < end; j += 2) {
    int s0 = csrc[j], s1 = csrc[j + 1];
    float w0 = dinv[s0], w1 = dinv[s1];
    ushort2 u0 = *(const ushort2*)(xb + (long)s0 * D + 2 * lane);
    ushort2 u1 = *(const ushort2*)(xb + (long)s1 * D + 2 * lane);
    float a0 = bf2f(u0.x), b0 = bf2f(u0.y);
    float a1 = bf2f(u1.x), b1 = bf2f(u1.y);
    sg.x += a0 + a1;
    sg.y += b0 + b1;
    sc.x = fmaf(w0, a0, fmaf(w1, a1, sc.x));
    sc.y = fmaf(w0, b0, fmaf(w1, b1, sc.y));
  }
  if (j < end) {
    int s0 = csrc[j];
    float w0 = dinv[s0];
    ushort2 u0 = *(const ushort2*)(xb + (long)s0 * D + 2 * lane);
    float a0 = bf2f(u0.x), b0 = bf2f(u0.y);
    sg.x += a0; sg.y += b0;
    sc.x = fmaf(w0, a0, sc.x);
    sc.y = fmaf(w0, b0, sc.y);
  }
  ushort2 us = *(const ushort2*)(xb + (long)nd * D + 2 * lane);
  float xs = bf2f(us.x), ys = bf2f(us.y);
  float dd = dinv[nd];
  ushort2 oc, og;
  oc.x = f2bf(dd * (sc.x + dd * xs));
  oc.y = f2bf(dd * (sc.y + dd * ys));
  og.x = f2bf(xs + sg.x);
  og.y = f2bf(ys + sg.y);
  *(ushort2*)(ab + (long)nd * 256 + 2 * lane) = oc;
  *(ushort2*)(ab + (long)nd * 256 + 128 + 2 * lane) = og;
}

// ---------------------------------------------------------------------------
// gather B: input hg[node][256] = [h|g]; one ushort4 load per edge per lane.
// lanes 0-31: GCN half (scale by dinv[s]); lanes 32-63: GIN half.
// Output ab2[node][256] = [gcn2 | gin2] bf16.
// ---------------------------------------------------------------------------
__global__ __launch_bounds__(256) void gatherB_kernel(
    const ushort* __restrict__ hg, const float* __restrict__ dinv,
    const int* __restrict__ rowptr, const int* __restrict__ csrc,
    ushort* __restrict__ ab2, int n) {
  int nd = blockIdx.x * 4 + (threadIdx.x >> 6);
  if (nd >= n) return;
  int lane = threadIdx.x & 63;
  int half = lane >> 5;
  int beg = rowptr[nd], end = rowptr[nd + 1];
  float4 s = make_float4(0.f, 0.f, 0.f, 0.f);
  int j = beg;
  for (; j + 1 < end; j += 2) {
    int s0 = csrc[j], s1 = csrc[j + 1];
    float w0 = dinv[s0], w1 = dinv[s1];
    ushort4 v0 = *(const ushort4*)(hg + (long)s0 * 256 + lane * 4);
    ushort4 v1 = *(const ushort4*)(hg + (long)s1 * 256 + lane * 4);
    float c0 = half ? 1.f : w0;
    float c1 = half ? 1.f : w1;
    s.x = fmaf(c0, bf2f(v0.x), fmaf(c1, bf2f(v1.x), s.x));
    s.y = fmaf(c0, bf2f(v0.y), fmaf(c1, bf2f(v1.y), s.y));
    s.z = fmaf(c0, bf2f(v0.z), fmaf(c1, bf2f(v1.z), s.z));
    s.w = fmaf(c0, bf2f(v0.w), fmaf(c1, bf2f(v1.w), s.w));
  }
  if (j < end) {
    int s0 = csrc[j];
    float w0 = dinv[s0];
    ushort4 v0 = *(const ushort4*)(hg + (long)s0 * 256 + lane * 4);
    float c0 = half ? 1.f : w0;
    s.x = fmaf(c0, bf2f(v0.x), s.x);
    s.y = fmaf(c0, bf2f(v0.y), s.y);
    s.z = fmaf(c0, bf2f(v0.z), s.z);
    s.w = fmaf(c0, bf2f(v0.w), s.w);
  }
  ushort4 u = *(const ushort4*)(hg + (long)nd * 256 + lane * 4);
  float dd = dinv[nd];
  float4 o;
  if (half == 0) {
    o.x = dd * (s.x + dd * bf2f(u.x));
    o.y = dd * (s.y + dd * bf2f(u.y));
    o.z = dd * (s.z + dd * bf2f(u.z));
    o.w = dd * (s.w + dd * bf2f(u.w));
  } else {
    o.x = s.x + bf2f(u.x);
    o.y = s.y + bf2f(u.y);
    o.z = s.z + bf2f(u.z);
    o.w = s.w + bf2f(u.w);
  }
  ushort4 r;
  r.x = f2bf(o.x); r.y = f2bf(o.y); r.z = f2bf(o.z); r.w = f2bf(o.w);
  *(ushort4*)(ab2 + (long)nd * 256 + lane * 4) = r;
}

// ---------------------------------------------------------------------------
// layer-1 MFMA GEMM, both branches in one launch (blockIdx.y: 0=GCN+relu, 1=GIN).
// A interleaved [node][256]; output interleaved hg[node][256].
// ---------------------------------------------------------------------------
__global__ __launch_bounds__(256) void gemm1_kernel(
    const ushort* __restrict__ ab,
    const ushort* __restrict__ Wg, const ushort* __restrict__ Wi,
    const float* __restrict__ bg, const float* __restrict__ bi,
    ushort* __restrict__ hg, int n) {
  const int y = blockIdx.y;
  const ushort* __restrict__ Wt = y ? Wi : Wg;
  const float* __restrict__ bias = y ? bi : bg;
  __shared__ ushort Ws[128 * 128];
  const int tid = threadIdx.x;
  const int wave = tid >> 6, lane = tid & 63;
  const int rlo = lane & 15, khi = lane >> 4;
  const int rb = blockIdx.x * 128 + wave * 32;

  s8v a[2][4];
#pragma unroll
  for (int rt = 0; rt < 2; ++rt) {
    int row = rb + rt * 16 + rlo;
    row = row < n ? row : n - 1;
    const ushort* p = ab + (long)row * 256 + y * 128 + khi * 8;
#pragma unroll
    for (int ks = 0; ks < 4; ++ks) a[rt][ks] = *(const s8v*)(p + ks * 32);
  }

#pragma unroll
  for (int j = 0; j < 8; ++j) {
    int q = tid + 256 * j;
    int c = q >> 4, kc = q & 15;
    *(s8v*)&Ws[c * 128 + ((kc ^ (c & 7)) << 3)] = *(const s8v*)(Wt + c * 128 + kc * 8);
  }
  __syncthreads();

  f4v acc[2][8];
#pragma unroll
  for (int rt = 0; rt < 2; ++rt)
#pragma unroll
    for (int ct = 0; ct < 8; ++ct) acc[rt][ct] = (f4v){0.f, 0.f, 0.f, 0.f};

#pragma unroll
  for (int ks = 0; ks < 4; ++ks) {
#pragma unroll
    for (int ct = 0; ct < 8; ++ct) {
      int c = ct * 16 + rlo;
      int kc = ks * 4 + khi;
      s8v b = *(const s8v*)&Ws[c * 128 + ((kc ^ (c & 7)) << 3)];
      acc[0][ct] = __builtin_amdgcn_mfma_f32_16x16x32_bf16(a[0][ks], b, acc[0][ct], 0, 0, 0);
      acc[1][ct] = __builtin_amdgcn_mfma_f32_16x16x32_bf16(a[1][ks], b, acc[1][ct], 0, 0, 0);
    }
  }

#pragma unroll
  for (int ct = 0; ct < 8; ++ct) {
    int col = ct * 16 + rlo;
    float bb = bias[col];
#pragma unroll
    for (int rt = 0; rt < 2; ++rt) {
#pragma unroll
      for (int i = 0; i < 4; ++i) {
        int row = rb + rt * 16 + 4 * khi + i;
        if (row < n) {
          float v = acc[rt][ct][i] + bb;
          if (y == 0) v = fmaxf(v, 0.f);
          hg[(long)row * 256 + y * 128 + col] = f2bf(v);
        }
      }
    }
  }
}

// ---------------------------------------------------------------------------
// final dual MFMA GEMM: out = A_gcn@Wt2gT + A_gin@Wt2iT + btot (f32 out)
// A interleaved ab2[node][256].
// ---------------------------------------------------------------------------
__global__ __launch_bounds__(256) void gemm2_kernel(
    const ushort* __restrict__ ab2,
    const ushort* __restrict__ Wt2g, const ushort* __restrict__ Wt2i,
    const float* __restrict__ btot, float* __restrict__ out, int n) {
  __shared__ ushort Ws[2 * 128 * 128];
  const int tid = threadIdx.x;
  const int wave = tid >> 6, lane = tid & 63;
  const int rlo = lane & 15, khi = lane >> 4;
  const int rb = blockIdx.x * 128 + wave * 32;

  s8v a1[2][4], a2[2][4];
#pragma unroll
  for (int rt = 0; rt < 2; ++rt) {
    int row = rb + rt * 16 + rlo;
    row = row < n ? row : n - 1;
    const ushort* p = ab2 + (long)row * 256 + khi * 8;
#pragma unroll
    for (int ks = 0; ks < 4; ++ks) a1[rt][ks] = *(const s8v*)(p + ks * 32);
#pragma unroll
    for (int ks = 0; ks < 4; ++ks) a2[rt][ks] = *(const s8v*)(p + 128 + ks * 32);
  }

#pragma unroll
  for (int j = 0; j < 8; ++j) {
    int q = tid + 256 * j;
    int c = q >> 4, kc = q & 15;
    *(s8v*)&Ws[c * 128 + ((kc ^ (c & 7)) << 3)] = *(const s8v*)(Wt2g + c * 128 + kc * 8);
  }
#pragma unroll
  for (int j = 0; j < 8; ++j) {
    int q = tid + 256 * j;
    int c = q >> 4, kc = q & 15;
    *(s8v*)&Ws[128 * 128 + c * 128 + ((kc ^ (c & 7)) << 3)] =
        *(const s8v*)(Wt2i + c * 128 + kc * 8);
  }
  __syncthreads();

  f4v acc[2][8];
#pragma unroll
  for (int rt = 0; rt < 2; ++rt)
#pragma unroll
    for (int ct = 0; ct < 8; ++ct) acc[rt][ct] = (f4v){0.f, 0.f, 0.f, 0.f};

#pragma unroll
  for (int ks = 0; ks < 4; ++ks) {
#pragma unroll
    for (int ct = 0; ct < 8; ++ct) {
      int c = ct * 16 + rlo;
      int kc = ks * 4 + khi;
      s8v b = *(const s8v*)&Ws[c * 128 + ((kc ^ (c & 7)) << 3)];
      acc[0][ct] = __builtin_amdgcn_mfma_f32_16x16x32_bf16(a1[0][ks], b, acc[0][ct], 0, 0, 0);
      acc[1][ct] = __builtin_amdgcn_mfma_f32_16x16x32_bf16(a1[1][ks], b, acc[1][ct], 0, 0, 0);
    }
  }
#pragma unroll
  for (int ks = 0; ks < 4; ++ks) {
#pragma unroll
    for (int ct = 0; ct < 8; ++ct) {
      int c = ct * 16 + rlo;
      int kc = ks * 4 + khi;
      s8v b = *(const s8v*)&Ws[128 * 128 + c * 128 + ((kc ^ (c & 7)) << 3)];
      acc[0][ct] = __builtin_amdgcn_mfma_f32_16x16x32_bf16(a2[0][ks], b, acc[0][ct], 0, 0, 0);
      acc[1][ct] = __builtin_amdgcn_mfma_f32_16x16x32_bf16(a2[1][ks], b, acc[1][ct], 0, 0, 0);
    }
  }

#pragma unroll
  for (int ct = 0; ct < 8; ++ct) {
    int col = ct * 16 + rlo;
    float bb = btot[col];
#pragma unroll
    for (int rt = 0; rt < 2; ++rt) {
#pragma unroll
      for (int i = 0; i < 4; ++i) {
        int row = rb + rt * 16 + 4 * khi + i;
        if (row < n)
          out[(long)row * D + col] = acc[rt][ct][i] + bb;
      }
    }
  }
}

// ---------------------------------------------------------------------------
extern "C" void kernel_launch(void* const* d_in, const int* in_sizes, int n_in,
                              void* d_out, int out_size, void* d_ws, size_t ws_size,
                              hipStream_t stream) {
  const float* x   = (const float*)d_in[0];
  const int*   ei  = (const int*)d_in[1];
  const float* gw1 = (const float*)d_in[2];
  const float* gb1 = (const float*)d_in[3];
  const float* gw2 = (const float*)d_in[4];
  const float* gb2 = (const float*)d_in[5];
  const float* iw1 = (const float*)d_in[6];
  const float* ib1 = (const float*)d_in[7];
  const float* iw2 = (const float*)d_in[8];
  const float* ib2 = (const float*)d_in[9];
  const float* lw  = (const float*)d_in[10];
  const float* lb  = (const float*)d_in[11];
  const float* fw  = (const float*)d_in[12];
  const float* fb  = (const float*)d_in[13];
  float* out = (float*)d_out;

  const int n = in_sizes[0] / D;
  const int E = in_sizes[1] / 2;
  const int* src = ei;
  const int* dst = ei + E;
  const int nb = (n + 255) / 256;
  const long ND = (long)n * D;

  char* p = (char*)d_ws;
  auto alloc = [&](size_t bytes) {
    char* r = p;
    p += (bytes + 255) & ~(size_t)255;
    return r;
  };
  int* ideg    = (int*)alloc((size_t)n * 4);
  int* incl    = (int*)alloc((size_t)n * 4);
  int* rowptr  = (int*)alloc((size_t)(n + 1) * 4);
  int* bsum    = (int*)alloc(1024 * 4);
  int* pos     = (int*)alloc((size_t)E * 4);
  int* csrc    = (int*)alloc((size_t)E * 4);
  float* dinv  = (float*)alloc((size_t)n * 4);
  float* LF    = (float*)alloc(16384 * 4);
  float* btot  = (float*)alloc(128 * 4);
  ushort* xb   = (ushort*)alloc(ND * 2);
  ushort* Wt1g = (ushort*)alloc(16384 * 2);
  ushort* Wt1i = (ushort*)alloc(16384 * 2);
  ushort* Wt2g = (ushort*)alloc(16384 * 2);
  ushort* Wt2i = (ushort*)alloc(16384 * 2);
  ushort* ab   = (ushort*)alloc(2 * ND * 2);  // gatherA out / gemm1 in; reused by gatherB out
  ushort* hg   = (ushort*)alloc(2 * ND * 2);  // gemm1 out / gatherB in

  hipMemsetAsync(ideg, 0, (size_t)n * 4, stream);

  // CSR build
  degpos_kernel<<<2048, 256, 0, stream>>>(dst, ideg, pos, E);
  scan1_kernel<<<nb, 256, 0, stream>>>(ideg, incl, bsum, n);
  scan2_kernel<<<1, 256, 0, stream>>>(bsum, nb);
  scan3_kernel<<<nb, 256, 0, stream>>>(ideg, incl, bsum, rowptr, dinv, n, E);
  scatter_kernel<<<2048, 256, 0, stream>>>(src, dst, rowptr, pos, csrc, E);

  // conversions + weight folds
  xcvt_kernel<<<2048, 256, 0, stream>>>(x, xb, ND);
  prep1_kernel<<<192, 256, 0, stream>>>(gw1, iw1, Wt1g, Wt1i, lw, fw, LF);
  prep2_kernel<<<129, 256, 0, stream>>>(gw2, iw2, LF, Wt2g, Wt2i, gb2, ib2, lb, fw, fb, btot);

  // layer 1
  gatherA_kernel<<<(n + 3) / 4, 256, 0, stream>>>(xb, dinv, rowptr, csrc, ab, n);
  const int nblk = (n + 127) / 128;
  gemm1_kernel<<<dim3(nblk, 2), 256, 0, stream>>>(ab, Wt1g, Wt1i, gb1, ib1, hg, n);

  // layer 2 + folded linear tail
  gatherB_kernel<<<(n + 3) / 4, 256, 0, stream>>>(hg, dinv, rowptr, csrc, ab, n);
  gemm2_kernel<<<nblk, 256, 0, stream>>>(ab, Wt2g, Wt2i, btot, out, n);
}

// Round 5
// 425.917 us; speedup vs baseline: 36.8794x; 1.0949x over previous
//
#include <hip/hip_runtime.h>

#define D 128

using s8v = __attribute__((ext_vector_type(8))) short;
using f4v = __attribute__((ext_vector_type(4))) float;

__device__ __forceinline__ float bf2f(ushort u) {
  union { uint i; float f; } v; v.i = ((uint)u) << 16; return v.f;
}
__device__ __forceinline__ ushort f2bf(float f) {
  union { float f; uint i; } v; v.f = f;
  uint b = v.i;
  return (ushort)((b + 0x7fffu + ((b >> 16) & 1u)) >> 16);
}

// ---------------------------------------------------------------------------
// degree histogram + per-edge slot: pos[e] = old count of dst[e]
// ---------------------------------------------------------------------------
__global__ void degpos_kernel(const int* __restrict__ dst, int* __restrict__ ideg,
                              int* __restrict__ pos, int E) {
  int i = blockIdx.x * blockDim.x + threadIdx.x;
  int stride = gridDim.x * blockDim.x;
  for (int e = i; e < E; e += stride)
    pos[e] = atomicAdd(&ideg[dst[e]], 1);
}

// ---------------------------------------------------------------------------
// 3-kernel exclusive scan over ideg[n] -> rowptr[n+1]; scan3 also emits dinv
// ---------------------------------------------------------------------------
__global__ void scan1_kernel(const int* __restrict__ deg, int* __restrict__ incl,
                             int* __restrict__ bsum, int n) {
  __shared__ int tmp[256];
  int t = threadIdx.x;
  int i = blockIdx.x * 256 + t;
  int v = (i < n) ? deg[i] : 0;
  tmp[t] = v;
  __syncthreads();
#pragma unroll
  for (int off = 1; off < 256; off <<= 1) {
    int u = (t >= off) ? tmp[t - off] : 0;
    __syncthreads();
    tmp[t] += u;
    __syncthreads();
  }
  if (i < n) incl[i] = tmp[t];
  if (t == 255) bsum[blockIdx.x] = tmp[255];
}

__global__ void scan2_kernel(int* __restrict__ bsum, int nb) {
  __shared__ int tmp[256];
  __shared__ int carry_s;
  int t = threadIdx.x;
  if (t == 0) carry_s = 0;
  __syncthreads();
  for (int base = 0; base < nb; base += 256) {
    int v = (base + t < nb) ? bsum[base + t] : 0;
    tmp[t] = v;
    __syncthreads();
#pragma unroll
    for (int off = 1; off < 256; off <<= 1) {
      int u = (t >= off) ? tmp[t - off] : 0;
      __syncthreads();
      tmp[t] += u;
      __syncthreads();
    }
    int inc = tmp[t] + carry_s;
    if (base + t < nb) bsum[base + t] = inc;
    __syncthreads();
    if (t == 255) carry_s = inc;
    __syncthreads();
  }
}

__global__ void scan3_kernel(const int* __restrict__ deg, const int* __restrict__ incl,
                             const int* __restrict__ bsum, int* __restrict__ rowptr,
                             float* __restrict__ dinv, int n, int E) {
  int i = blockIdx.x * 256 + threadIdx.x;
  if (i < n) {
    int carry = (blockIdx.x > 0) ? bsum[blockIdx.x - 1] : 0;
    int d = deg[i];
    rowptr[i] = incl[i] - d + carry;
    dinv[i] = rsqrtf((float)d + 1.0f);
  }
  if (i == 0) rowptr[n] = E;
}

// scatter (no atomics): csrc[rowptr[d] + pos[e]] = src[e]
__global__ void scatter_kernel(const int* __restrict__ src, const int* __restrict__ dst,
                               const int* __restrict__ rowptr, const int* __restrict__ pos,
                               int* __restrict__ csrc, int E) {
  int i = blockIdx.x * blockDim.x + threadIdx.x;
  int stride = gridDim.x * blockDim.x;
  for (int e = i; e < E; e += stride)
    csrc[rowptr[dst[e]] + pos[e]] = src[e];
}

// ---------------------------------------------------------------------------
// x (f32) -> xb (bf16), 8 elems/thread
// ---------------------------------------------------------------------------
__global__ void xcvt_kernel(const float* __restrict__ x, ushort* __restrict__ xb, long total) {
  long i = ((long)blockIdx.x * blockDim.x + threadIdx.x) * 8;
  long stride = (long)gridDim.x * blockDim.x * 8;
  for (long t = i; t < total; t += stride) {
    float4 v0 = *(const float4*)(x + t);
    float4 v1 = *(const float4*)(x + t + 4);
    s8v u;
    u[0] = (short)f2bf(v0.x); u[1] = (short)f2bf(v0.y);
    u[2] = (short)f2bf(v0.z); u[3] = (short)f2bf(v0.w);
    u[4] = (short)f2bf(v1.x); u[5] = (short)f2bf(v1.y);
    u[6] = (short)f2bf(v1.z); u[7] = (short)f2bf(v1.w);
    *(s8v*)(xb + t) = u;
  }
}

// prep1: blocks 0-127 transpose gw1/iw1 to bf16 [c][k]; blocks 128-191: LF = lw@fw
__global__ void prep1_kernel(const float* __restrict__ gw1, const float* __restrict__ iw1,
                             ushort* __restrict__ Wt1g, ushort* __restrict__ Wt1i,
                             const float* __restrict__ lw, const float* __restrict__ fw,
                             float* __restrict__ LF) {
  int b = blockIdx.x;
  if (b < 128) {
    int t = b * 256 + threadIdx.x;
    int which = t >> 14, q = t & 16383;
    int k = q >> 7, c = q & 127;
    const float* w = which ? iw1 : gw1;
    ushort* o = which ? Wt1i : Wt1g;
    o[c * 128 + k] = f2bf(w[k * 128 + c]);
  } else {
    int t = (b - 128) * 256 + threadIdx.x;
    int r = t >> 7, c = t & 127;
    float s = 0.f;
#pragma unroll 8
    for (int k = 0; k < 128; ++k) s = fmaf(lw[r * 128 + k], fw[k * 128 + c], s);
    LF[r * 128 + c] = s;
  }
}

// prep2: blocks 0-127: WtT2{g,i} = bf16T(w2@LF); block 128: folded bias
__global__ void prep2_kernel(const float* __restrict__ gw2, const float* __restrict__ iw2,
                             const float* __restrict__ LF,
                             ushort* __restrict__ Wt2g, ushort* __restrict__ Wt2i,
                             const float* __restrict__ gb2, const float* __restrict__ ib2,
                             const float* __restrict__ lb, const float* __restrict__ fw,
                             const float* __restrict__ fb, float* __restrict__ btot) {
  int b = blockIdx.x;
  if (b < 128) {
    int t = b * 256 + threadIdx.x;
    int which = t >> 14, q = t & 16383;
    int k = q >> 7, c = q & 127;
    const float* W = which ? iw2 : gw2;
    ushort* O = which ? Wt2i : Wt2g;
    float s = 0.f;
#pragma unroll 8
    for (int j = 0; j < 128; ++j) s = fmaf(W[k * 128 + j], LF[j * 128 + c], s);
    O[c * 128 + k] = f2bf(s);
  } else if (threadIdx.x < 128) {
    int c = threadIdx.x;
    float s = fb[c];
#pragma unroll 8
    for (int j = 0; j < 128; ++j) {
      s = fmaf(gb2[j] + ib2[j], LF[j * 128 + c], s);
      s = fmaf(2.f * lb[j], fw[j * 128 + c], s);
    }
    btot[c] = s;
  }
}

// ---------------------------------------------------------------------------
// gather A: wave per dst node; HALVES process alternate edges (half = lane>>5),
// each half-lane covers features 4*(lane&31).. +3 via 8B ushort4 loads.
// 4 edges per half in flight (unroll) -> 32B outstanding per lane.
// Halves combined with shfl_xor(32); half0 writes GCN row, half1 GIN row.
// Output ab[node][256] = [gcn(128) | gin(128)] bf16.
// ---------------------------------------------------------------------------
__global__ __launch_bounds__(256) void gatherA_kernel(
    const ushort* __restrict__ xb, const float* __restrict__ dinv,
    const int* __restrict__ rowptr, const int* __restrict__ csrc,
    ushort* __restrict__ ab, int n) {
  int nd = blockIdx.x * 4 + (threadIdx.x >> 6);
  if (nd >= n) return;
  int lane = threadIdx.x & 63;
  int half = lane >> 5;
  int hl = lane & 31;
  int beg = rowptr[nd], end = rowptr[nd + 1];
  float4 sg = make_float4(0.f, 0.f, 0.f, 0.f);
  float4 sc = make_float4(0.f, 0.f, 0.f, 0.f);
  int j = beg + half;
  // 4 edges per half per iteration (edges j, j+2, j+4, j+6 for this half)
  for (; j + 6 < end; j += 8) {
    int s0 = csrc[j], s1 = csrc[j + 2], s2 = csrc[j + 4], s3 = csrc[j + 6];
    float w0 = dinv[s0], w1 = dinv[s1], w2 = dinv[s2], w3 = dinv[s3];
    ushort4 v0 = *(const ushort4*)(xb + (long)s0 * D + 4 * hl);
    ushort4 v1 = *(const ushort4*)(xb + (long)s1 * D + 4 * hl);
    ushort4 v2 = *(const ushort4*)(xb + (long)s2 * D + 4 * hl);
    ushort4 v3 = *(const ushort4*)(xb + (long)s3 * D + 4 * hl);
    float a0 = bf2f(v0.x), a1 = bf2f(v0.y), a2 = bf2f(v0.z), a3 = bf2f(v0.w);
    sg.x += a0; sg.y += a1; sg.z += a2; sg.w += a3;
    sc.x = fmaf(w0, a0, sc.x); sc.y = fmaf(w0, a1, sc.y);
    sc.z = fmaf(w0, a2, sc.z); sc.w = fmaf(w0, a3, sc.w);
    a0 = bf2f(v1.x); a1 = bf2f(v1.y); a2 = bf2f(v1.z); a3 = bf2f(v1.w);
    sg.x += a0; sg.y += a1; sg.z += a2; sg.w += a3;
    sc.x = fmaf(w1, a0, sc.x); sc.y = fmaf(w1, a1, sc.y);
    sc.z = fmaf(w1, a2, sc.z); sc.w = fmaf(w1, a3, sc.w);
    a0 = bf2f(v2.x); a1 = bf2f(v2.y); a2 = bf2f(v2.z); a3 = bf2f(v2.w);
    sg.x += a0; sg.y += a1; sg.z += a2; sg.w += a3;
    sc.x = fmaf(w2, a0, sc.x); sc.y = fmaf(w2, a1, sc.y);
    sc.z = fmaf(w2, a2, sc.z); sc.w = fmaf(w2, a3, sc.w);
    a0 = bf2f(v3.x); a1 = bf2f(v3.y); a2 = bf2f(v3.z); a3 = bf2f(v3.w);
    sg.x += a0; sg.y += a1; sg.z += a2; sg.w += a3;
    sc.x = fmaf(w3, a0, sc.x); sc.y = fmaf(w3, a1, sc.y);
    sc.z = fmaf(w3, a2, sc.z); sc.w = fmaf(w3, a3, sc.w);
  }
  for (; j < end; j += 2) {
    int s0 = csrc[j];
    float w0 = dinv[s0];
    ushort4 v0 = *(const ushort4*)(xb + (long)s0 * D + 4 * hl);
    float a0 = bf2f(v0.x), a1 = bf2f(v0.y), a2 = bf2f(v0.z), a3 = bf2f(v0.w);
    sg.x += a0; sg.y += a1; sg.z += a2; sg.w += a3;
    sc.x = fmaf(w0, a0, sc.x); sc.y = fmaf(w0, a1, sc.y);
    sc.z = fmaf(w0, a2, sc.z); sc.w = fmaf(w0, a3, sc.w);
  }
  // combine halves
  sg.x += __shfl_xor(sg.x, 32); sg.y += __shfl_xor(sg.y, 32);
  sg.z += __shfl_xor(sg.z, 32); sg.w += __shfl_xor(sg.w, 32);
  sc.x += __shfl_xor(sc.x, 32); sc.y += __shfl_xor(sc.y, 32);
  sc.z += __shfl_xor(sc.z, 32); sc.w += __shfl_xor(sc.w, 32);

  ushort4 us = *(const ushort4*)(xb + (long)nd * D + 4 * hl);
  float x0 = bf2f(us.x), x1 = bf2f(us.y), x2 = bf2f(us.z), x3 = bf2f(us.w);
  float dd = dinv[nd];
  ushort4 o;
  if (half == 0) {  // GCN row
    o.x = f2bf(dd * (sc.x + dd * x0));
    o.y = f2bf(dd * (sc.y + dd * x1));
    o.z = f2bf(dd * (sc.z + dd * x2));
    o.w = f2bf(dd * (sc.w + dd * x3));
    *(ushort4*)(ab + (long)nd * 256 + 4 * hl) = o;
  } else {          // GIN row
    o.x = f2bf(x0 + sg.x);
    o.y = f2bf(x1 + sg.y);
    o.z = f2bf(x2 + sg.z);
    o.w = f2bf(x3 + sg.w);
    *(ushort4*)(ab + (long)nd * 256 + 128 + 4 * hl) = o;
  }
}

// ---------------------------------------------------------------------------
// gather B: input hg[node][256] = [h|g]; one ushort4 (8B) load per edge per
// lane, 4 edges in flight. lanes 0-31: GCN half (scale dinv[s]); 32-63: GIN.
// Output ab2[node][256] = [gcn2 | gin2] bf16.
// ---------------------------------------------------------------------------
__global__ __launch_bounds__(256) void gatherB_kernel(
    const ushort* __restrict__ hg, const float* __restrict__ dinv,
    const int* __restrict__ rowptr, const int* __restrict__ csrc,
    ushort* __restrict__ ab2, int n) {
  int nd = blockIdx.x * 4 + (threadIdx.x >> 6);
  if (nd >= n) return;
  int lane = threadIdx.x & 63;
  int half = lane >> 5;
  int beg = rowptr[nd], end = rowptr[nd + 1];
  float4 s = make_float4(0.f, 0.f, 0.f, 0.f);
  int j = beg;
  for (; j + 3 < end; j += 4) {
    int s0 = csrc[j], s1 = csrc[j + 1], s2 = csrc[j + 2], s3 = csrc[j + 3];
    float w0 = dinv[s0], w1 = dinv[s1], w2 = dinv[s2], w3 = dinv[s3];
    ushort4 v0 = *(const ushort4*)(hg + (long)s0 * 256 + lane * 4);
    ushort4 v1 = *(const ushort4*)(hg + (long)s1 * 256 + lane * 4);
    ushort4 v2 = *(const ushort4*)(hg + (long)s2 * 256 + lane * 4);
    ushort4 v3 = *(const ushort4*)(hg + (long)s3 * 256 + lane * 4);
    float c0 = half ? 1.f : w0;
    float c1 = half ? 1.f : w1;
    float c2 = half ? 1.f : w2;
    float c3 = half ? 1.f : w3;
    s.x = fmaf(c0, bf2f(v0.x), s.x); s.y = fmaf(c0, bf2f(v0.y), s.y);
    s.z = fmaf(c0, bf2f(v0.z), s.z); s.w = fmaf(c0, bf2f(v0.w), s.w);
    s.x = fmaf(c1, bf2f(v1.x), s.x); s.y = fmaf(c1, bf2f(v1.y), s.y);
    s.z = fmaf(c1, bf2f(v1.z), s.z); s.w = fmaf(c1, bf2f(v1.w), s.w);
    s.x = fmaf(c2, bf2f(v2.x), s.x); s.y = fmaf(c2, bf2f(v2.y), s.y);
    s.z = fmaf(c2, bf2f(v2.z), s.z); s.w = fmaf(c2, bf2f(v2.w), s.w);
    s.x = fmaf(c3, bf2f(v3.x), s.x); s.y = fmaf(c3, bf2f(v3.y), s.y);
    s.z = fmaf(c3, bf2f(v3.z), s.z); s.w = fmaf(c3, bf2f(v3.w), s.w);
  }
  for (; j < end; ++j) {
    int s0 = csrc[j];
    float w0 = dinv[s0];
    ushort4 v0 = *(const ushort4*)(hg + (long)s0 * 256 + lane * 4);
    float c0 = half ? 1.f : w0;
    s.x = fmaf(c0, bf2f(v0.x), s.x); s.y = fmaf(c0, bf2f(v0.y), s.y);
    s.z = fmaf(c0, bf2f(v0.z), s.z); s.w = fmaf(c0, bf2f(v0.w), s.w);
  }
  ushort4 u = *(const ushort4*)(hg + (long)nd * 256 + lane * 4);
  float dd = dinv[nd];
  float4 o;
  if (half == 0) {
    o.x = dd * (s.x + dd * bf2f(u.x));
    o.y = dd * (s.y + dd * bf2f(u.y));
    o.z = dd * (s.z + dd * bf2f(u.z));
    o.w = dd * (s.w + dd * bf2f(u.w));
  } else {
    o.x = s.x + bf2f(u.x);
    o.y = s.y + bf2f(u.y);
    o.z = s.z + bf2f(u.z);
    o.w = s.w + bf2f(u.w);
  }
  ushort4 r;
  r.x = f2bf(o.x); r.y = f2bf(o.y); r.z = f2bf(o.z); r.w = f2bf(o.w);
  *(ushort4*)(ab2 + (long)nd * 256 + lane * 4) = r;
}

// ---------------------------------------------------------------------------
// layer-1 MFMA GEMM, both branches in one launch (blockIdx.y: 0=GCN+relu, 1=GIN).
// A interleaved [node][256]; output interleaved hg[node][256].
// ---------------------------------------------------------------------------
__global__ __launch_bounds__(256) void gemm1_kernel(
    const ushort* __restrict__ ab,
    const ushort* __restrict__ Wg, const ushort* __restrict__ Wi,
    const float* __restrict__ bg, const float* __restrict__ bi,
    ushort* __restrict__ hg, int n) {
  const int y = blockIdx.y;
  const ushort* __restrict__ Wt = y ? Wi : Wg;
  const float* __restrict__ bias = y ? bi : bg;
  __shared__ ushort Ws[128 * 128];
  const int tid = threadIdx.x;
  const int wave = tid >> 6, lane = tid & 63;
  const int rlo = lane & 15, khi = lane >> 4;
  const int rb = blockIdx.x * 128 + wave * 32;

  s8v a[2][4];
#pragma unroll
  for (int rt = 0; rt < 2; ++rt) {
    int row = rb + rt * 16 + rlo;
    row = row < n ? row : n - 1;
    const ushort* p = ab + (long)row * 256 + y * 128 + khi * 8;
#pragma unroll
    for (int ks = 0; ks < 4; ++ks) a[rt][ks] = *(const s8v*)(p + ks * 32);
  }

#pragma unroll
  for (int j = 0; j < 8; ++j) {
    int q = tid + 256 * j;
    int c = q >> 4, kc = q & 15;
    *(s8v*)&Ws[c * 128 + ((kc ^ (c & 7)) << 3)] = *(const s8v*)(Wt + c * 128 + kc * 8);
  }
  __syncthreads();

  f4v acc[2][8];
#pragma unroll
  for (int rt = 0; rt < 2; ++rt)
#pragma unroll
    for (int ct = 0; ct < 8; ++ct) acc[rt][ct] = (f4v){0.f, 0.f, 0.f, 0.f};

#pragma unroll
  for (int ks = 0; ks < 4; ++ks) {
#pragma unroll
    for (int ct = 0; ct < 8; ++ct) {
      int c = ct * 16 + rlo;
      int kc = ks * 4 + khi;
      s8v b = *(const s8v*)&Ws[c * 128 + ((kc ^ (c & 7)) << 3)];
      acc[0][ct] = __builtin_amdgcn_mfma_f32_16x16x32_bf16(a[0][ks], b, acc[0][ct], 0, 0, 0);
      acc[1][ct] = __builtin_amdgcn_mfma_f32_16x16x32_bf16(a[1][ks], b, acc[1][ct], 0, 0, 0);
    }
  }

#pragma unroll
  for (int ct = 0; ct < 8; ++ct) {
    int col = ct * 16 + rlo;
    float bb = bias[col];
#pragma unroll
    for (int rt = 0; rt < 2; ++rt) {
#pragma unroll
      for (int i = 0; i < 4; ++i) {
        int row = rb + rt * 16 + 4 * khi + i;
        if (row < n) {
          float v = acc[rt][ct][i] + bb;
          if (y == 0) v = fmaxf(v, 0.f);
          hg[(long)row * 256 + y * 128 + col] = f2bf(v);
        }
      }
    }
  }
}

// ---------------------------------------------------------------------------
// final dual MFMA GEMM: out = A_gcn@Wt2gT + A_gin@Wt2iT + btot (f32 out)
// A interleaved ab2[node][256].
// ---------------------------------------------------------------------------
__global__ __launch_bounds__(256) void gemm2_kernel(
    const ushort* __restrict__ ab2,
    const ushort* __restrict__ Wt2g, const ushort* __restrict__ Wt2i,
    const float* __restrict__ btot, float* __restrict__ out, int n) {
  __shared__ ushort Ws[2 * 128 * 128];
  const int tid = threadIdx.x;
  const int wave = tid >> 6, lane = tid & 63;
  const int rlo = lane & 15, khi = lane >> 4;
  const int rb = blockIdx.x * 128 + wave * 32;

  s8v a1[2][4], a2[2][4];
#pragma unroll
  for (int rt = 0; rt < 2; ++rt) {
    int row = rb + rt * 16 + rlo;
    row = row < n ? row : n - 1;
    const ushort* p = ab2 + (long)row * 256 + khi * 8;
#pragma unroll
    for (int ks = 0; ks < 4; ++ks) a1[rt][ks] = *(const s8v*)(p + ks * 32);
#pragma unroll
    for (int ks = 0; ks < 4; ++ks) a2[rt][ks] = *(const s8v*)(p + 128 + ks * 32);
  }

#pragma unroll
  for (int j = 0; j < 8; ++j) {
    int q = tid + 256 * j;
    int c = q >> 4, kc = q & 15;
    *(s8v*)&Ws[c * 128 + ((kc ^ (c & 7)) << 3)] = *(const s8v*)(Wt2g + c * 128 + kc * 8);
  }
#pragma unroll
  for (int j = 0; j < 8; ++j) {
    int q = tid + 256 * j;
    int c = q >> 4, kc = q & 15;
    *(s8v*)&Ws[128 * 128 + c * 128 + ((kc ^ (c & 7)) << 3)] =
        *(const s8v*)(Wt2i + c * 128 + kc * 8);
  }
  __syncthreads();

  f4v acc[2][8];
#pragma unroll
  for (int rt = 0; rt < 2; ++rt)
#pragma unroll
    for (int ct = 0; ct < 8; ++ct) acc[rt][ct] = (f4v){0.f, 0.f, 0.f, 0.f};

#pragma unroll
  for (int ks = 0; ks < 4; ++ks) {
#pragma unroll
    for (int ct = 0; ct < 8; ++ct) {
      int c = ct * 16 + rlo;
      int kc = ks * 4 + khi;
      s8v b = *(const s8v*)&Ws[c * 128 + ((kc ^ (c & 7)) << 3)];
      acc[0][ct] = __builtin_amdgcn_mfma_f32_16x16x32_bf16(a1[0][ks], b, acc[0][ct], 0, 0, 0);
      acc[1][ct] = __builtin_amdgcn_mfma_f32_16x16x32_bf16(a1[1][ks], b, acc[1][ct], 0, 0, 0);
    }
  }
#pragma unroll
  for (int ks = 0; ks < 4; ++ks) {
#pragma unroll
    for (int ct = 0; ct < 8; ++ct) {
      int c = ct * 16 + rlo;
      int kc = ks * 4 + khi;
      s8v b = *(const s8v*)&Ws[128 * 128 + c * 128 + ((kc ^ (c & 7)) << 3)];
      acc[0][ct] = __builtin_amdgcn_mfma_f32_16x16x32_bf16(a2[0][ks], b, acc[0][ct], 0, 0, 0);
      acc[1][ct] = __builtin_amdgcn_mfma_f32_16x16x32_bf16(a2[1][ks], b, acc[1][ct], 0, 0, 0);
    }
  }

#pragma unroll
  for (int ct = 0; ct < 8; ++ct) {
    int col = ct * 16 + rlo;
    float bb = btot[col];
#pragma unroll
    for (int rt = 0; rt < 2; ++rt) {
#pragma unroll
      for (int i = 0; i < 4; ++i) {
        int row = rb + rt * 16 + 4 * khi + i;
        if (row < n)
          out[(long)row * D + col] = acc[rt][ct][i] + bb;
      }
    }
  }
}

// ---------------------------------------------------------------------------
extern "C" void kernel_launch(void* const* d_in, const int* in_sizes, int n_in,
                              void* d_out, int out_size, void* d_ws, size_t ws_size,
                              hipStream_t stream) {
  const float* x   = (const float*)d_in[0];
  const int*   ei  = (const int*)d_in[1];
  const float* gw1 = (const float*)d_in[2];
  const float* gb1 = (const float*)d_in[3];
  const float* gw2 = (const float*)d_in[4];
  const float* gb2 = (const float*)d_in[5];
  const float* iw1 = (const float*)d_in[6];
  const float* ib1 = (const float*)d_in[7];
  const float* iw2 = (const float*)d_in[8];
  const float* ib2 = (const float*)d_in[9];
  const float* lw  = (const float*)d_in[10];
  const float* lb  = (const float*)d_in[11];
  const float* fw  = (const float*)d_in[12];
  const float* fb  = (const float*)d_in[13];
  float* out = (float*)d_out;

  const int n = in_sizes[0] / D;
  const int E = in_sizes[1] / 2;
  const int* src = ei;
  const int* dst = ei + E;
  const int nb = (n + 255) / 256;
  const long ND = (long)n * D;

  char* p = (char*)d_ws;
  auto alloc = [&](size_t bytes) {
    char* r = p;
    p += (bytes + 255) & ~(size_t)255;
    return r;
  };
  int* ideg    = (int*)alloc((size_t)n * 4);
  int* incl    = (int*)alloc((size_t)n * 4);
  int* rowptr  = (int*)alloc((size_t)(n + 1) * 4);
  int* bsum    = (int*)alloc(1024 * 4);
  int* pos     = (int*)alloc((size_t)E * 4);
  int* csrc    = (int*)alloc((size_t)E * 4);
  float* dinv  = (float*)alloc((size_t)n * 4);
  float* LF    = (float*)alloc(16384 * 4);
  float* btot  = (float*)alloc(128 * 4);
  ushort* xb   = (ushort*)alloc(ND * 2);
  ushort* Wt1g = (ushort*)alloc(16384 * 2);
  ushort* Wt1i = (ushort*)alloc(16384 * 2);
  ushort* Wt2g = (ushort*)alloc(16384 * 2);
  ushort* Wt2i = (ushort*)alloc(16384 * 2);
  ushort* ab   = (ushort*)alloc(2 * ND * 2);  // gatherA out / gemm1 in; reused by gatherB out
  ushort* hg   = (ushort*)alloc(2 * ND * 2);  // gemm1 out / gatherB in

  hipMemsetAsync(ideg, 0, (size_t)n * 4, stream);

  // CSR build
  degpos_kernel<<<2048, 256, 0, stream>>>(dst, ideg, pos, E);
  scan1_kernel<<<nb, 256, 0, stream>>>(ideg, incl, bsum, n);
  scan2_kernel<<<1, 256, 0, stream>>>(bsum, nb);
  scan3_kernel<<<nb, 256, 0, stream>>>(ideg, incl, bsum, rowptr, dinv, n, E);
  scatter_kernel<<<2048, 256, 0, stream>>>(src, dst, rowptr, pos, csrc, E);

  // conversions + weight folds
  xcvt_kernel<<<2048, 256, 0, stream>>>(x, xb, ND);
  prep1_kernel<<<192, 256, 0, stream>>>(gw1, iw1, Wt1g, Wt1i, lw, fw, LF);
  prep2_kernel<<<129, 256, 0, stream>>>(gw2, iw2, LF, Wt2g, Wt2i, gb2, ib2, lb, fw, fb, btot);

  // layer 1
  gatherA_kernel<<<(n + 3) / 4, 256, 0, stream>>>(xb, dinv, rowptr, csrc, ab, n);
  const int nblk = (n + 127) / 128;
  gemm1_kernel<<<dim3(nblk, 2), 256, 0, stream>>>(ab, Wt1g, Wt1i, gb1, ib1, hg, n);

  // layer 2 + folded linear tail
  gatherB_kernel<<<(n + 3) / 4, 256, 0, stream>>>(hg, dinv, rowptr, csrc, ab, n);
  gemm2_kernel<<<nblk, 256, 0, stream>>>(ab, Wt2g, Wt2i, btot, out, n);
}

// Round 6
// 374.322 us; speedup vs baseline: 41.9626x; 1.1378x over previous
//
#include <hip/hip_runtime.h>

#define D 128
#define HS_LD 136  // h-tile LDS stride (ushorts): 272B rows, 16B-aligned, 2-way conflicts only

using s8v = __attribute__((ext_vector_type(8))) short;
using f4v = __attribute__((ext_vector_type(4))) float;

__device__ __forceinline__ float bf2f(ushort u) {
  union { uint i; float f; } v; v.i = ((uint)u) << 16; return v.f;
}
__device__ __forceinline__ ushort f2bf(float f) {
  union { float f; uint i; } v; v.f = f;
  uint b = v.i;
  return (ushort)((b + 0x7fffu + ((b >> 16) & 1u)) >> 16);
}

// ---------------------------------------------------------------------------
// megaA: blocks [0,2048) degpos | [2048,5248) xcvt | [5248,5312) LF=lw@fw |
//        [5312,5376) T1g = bf16T(gw1)
// ---------------------------------------------------------------------------
__global__ void megaA_kernel(const int* __restrict__ dst, int* __restrict__ ideg,
                             int* __restrict__ pos, int E,
                             const float* __restrict__ x, ushort* __restrict__ xb, long total,
                             const float* __restrict__ lw, const float* __restrict__ fw,
                             float* __restrict__ LF,
                             const float* __restrict__ gw1, ushort* __restrict__ T1g) {
  int b = blockIdx.x;
  if (b < 2048) {
    int i = b * 256 + threadIdx.x;
    int stride = 2048 * 256;
    for (int e = i; e < E; e += stride)
      pos[e] = atomicAdd(&ideg[dst[e]], 1);
  } else if (b < 5248) {
    long i = ((long)(b - 2048) * 256 + threadIdx.x) * 8;
    long stride = (long)3200 * 256 * 8;
    for (long t = i; t < total; t += stride) {
      float4 v0 = *(const float4*)(x + t);
      float4 v1 = *(const float4*)(x + t + 4);
      s8v u;
      u[0] = (short)f2bf(v0.x); u[1] = (short)f2bf(v0.y);
      u[2] = (short)f2bf(v0.z); u[3] = (short)f2bf(v0.w);
      u[4] = (short)f2bf(v1.x); u[5] = (short)f2bf(v1.y);
      u[6] = (short)f2bf(v1.z); u[7] = (short)f2bf(v1.w);
      *(s8v*)(xb + t) = u;
    }
  } else if (b < 5312) {
    int t = (b - 5248) * 256 + threadIdx.x;
    int r = t >> 7, c = t & 127;
    float s = 0.f;
#pragma unroll 8
    for (int k = 0; k < 128; ++k) s = fmaf(lw[r * 128 + k], fw[k * 128 + c], s);
    LF[r * 128 + c] = s;
  } else {
    int t = (b - 5312) * 256 + threadIdx.x;
    int k = t >> 7, c = t & 127;
    T1g[c * 128 + k] = f2bf(gw1[k * 128 + c]);
  }
}

// ---------------------------------------------------------------------------
// scanP: blocks [0,nb) scan1 | [nb,nb+64) M2i=iw2@LF | [nb+64,nb+128)
//        W2gT=bf16T(gw2@LF) | [nb+128] btot
// ---------------------------------------------------------------------------
__global__ void scanP_kernel(const int* __restrict__ deg, int* __restrict__ incl,
                             int* __restrict__ bsum, int n, int nb,
                             const float* __restrict__ iw2, const float* __restrict__ gw2,
                             const float* __restrict__ LF,
                             float* __restrict__ M2i, ushort* __restrict__ W2gT,
                             const float* __restrict__ gb2, const float* __restrict__ ib2,
                             const float* __restrict__ lb, const float* __restrict__ fw,
                             const float* __restrict__ fb, float* __restrict__ btot) {
  int b = blockIdx.x;
  if (b < nb) {
    __shared__ int tmp[256];
    int t = threadIdx.x;
    int i = b * 256 + t;
    int v = (i < n) ? deg[i] : 0;
    tmp[t] = v;
    __syncthreads();
#pragma unroll
    for (int off = 1; off < 256; off <<= 1) {
      int u = (t >= off) ? tmp[t - off] : 0;
      __syncthreads();
      tmp[t] += u;
      __syncthreads();
    }
    if (i < n) incl[i] = tmp[t];
    if (t == 255) bsum[b] = tmp[255];
  } else if (b < nb + 64) {
    int t = (b - nb) * 256 + threadIdx.x;
    int k = t >> 7, c = t & 127;
    float s = 0.f;
#pragma unroll 8
    for (int j = 0; j < 128; ++j) s = fmaf(iw2[k * 128 + j], LF[j * 128 + c], s);
    M2i[k * 128 + c] = s;
  } else if (b < nb + 128) {
    int t = (b - nb - 64) * 256 + threadIdx.x;
    int k = t >> 7, c = t & 127;
    float s = 0.f;
#pragma unroll 8
    for (int j = 0; j < 128; ++j) s = fmaf(gw2[k * 128 + j], LF[j * 128 + c], s);
    W2gT[c * 128 + k] = f2bf(s);
  } else if (threadIdx.x < 128) {
    int c = threadIdx.x;
    float s = fb[c];
#pragma unroll 8
    for (int j = 0; j < 128; ++j) {
      s = fmaf(gb2[j] + ib2[j], LF[j * 128 + c], s);
      s = fmaf(2.f * lb[j], fw[j * 128 + c], s);
    }
    btot[c] = s;
  }
}

// ---------------------------------------------------------------------------
// scan2F: block 0 scan2 | blocks [1,64] WginT=bf16T(iw1@M2i) | block 65 bgin
// ---------------------------------------------------------------------------
__global__ void scan2F_kernel(int* __restrict__ bsum, int nb,
                              const float* __restrict__ iw1, const float* __restrict__ M2i,
                              ushort* __restrict__ WginT,
                              const float* __restrict__ ib1, float* __restrict__ bgin) {
  int b = blockIdx.x;
  if (b == 0) {
    __shared__ int tmp[256];
    __shared__ int carry_s;
    int t = threadIdx.x;
    if (t == 0) carry_s = 0;
    __syncthreads();
    for (int base = 0; base < nb; base += 256) {
      int v = (base + t < nb) ? bsum[base + t] : 0;
      tmp[t] = v;
      __syncthreads();
#pragma unroll
      for (int off = 1; off < 256; off <<= 1) {
        int u = (t >= off) ? tmp[t - off] : 0;
        __syncthreads();
        tmp[t] += u;
        __syncthreads();
      }
      int inc = tmp[t] + carry_s;
      if (base + t < nb) bsum[base + t] = inc;
      __syncthreads();
      if (t == 255) carry_s = inc;
      __syncthreads();
    }
  } else if (b <= 64) {
    int t = (b - 1) * 256 + threadIdx.x;
    int k = t >> 7, c = t & 127;
    float s = 0.f;
#pragma unroll 8
    for (int j = 0; j < 128; ++j) s = fmaf(iw1[k * 128 + j], M2i[j * 128 + c], s);
    WginT[c * 128 + k] = f2bf(s);
  } else if (threadIdx.x < 128) {
    int c = threadIdx.x;
    float s = 0.f;
#pragma unroll 8
    for (int j = 0; j < 128; ++j) s = fmaf(ib1[j], M2i[j * 128 + c], s);
    bgin[c] = s;
  }
}

__global__ void scan3_kernel(const int* __restrict__ deg, const int* __restrict__ incl,
                             const int* __restrict__ bsum, int* __restrict__ rowptr,
                             float* __restrict__ dinv, int n, int E) {
  int i = blockIdx.x * 256 + threadIdx.x;
  if (i < n) {
    int carry = (blockIdx.x > 0) ? bsum[blockIdx.x - 1] : 0;
    int d = deg[i];
    rowptr[i] = incl[i] - d + carry;
    dinv[i] = rsqrtf((float)d + 1.0f);
  }
  if (i == 0) rowptr[n] = E;
}

// scatter (no atomics): csrc[rowptr[d] + pos[e]] = src[e]
__global__ void scatter_kernel(const int* __restrict__ src, const int* __restrict__ dst,
                               const int* __restrict__ rowptr, const int* __restrict__ pos,
                               int* __restrict__ csrc, int E) {
  int i = blockIdx.x * blockDim.x + threadIdx.x;
  int stride = gridDim.x * blockDim.x;
  for (int e = i; e < E; e += stride)
    csrc[rowptr[dst[e]] + pos[e]] = src[e];
}

// ---------------------------------------------------------------------------
// gather A (unchanged from r5): wave halves on alternate edges, 4-deep MLP,
// shfl_xor(32) combine; writes ab[node][256] = [gcn | gin] bf16.
// ---------------------------------------------------------------------------
__global__ __launch_bounds__(256) void gatherA_kernel(
    const ushort* __restrict__ xb, const float* __restrict__ dinv,
    const int* __restrict__ rowptr, const int* __restrict__ csrc,
    ushort* __restrict__ ab, int n) {
  int nd = blockIdx.x * 4 + (threadIdx.x >> 6);
  if (nd >= n) return;
  int lane = threadIdx.x & 63;
  int half = lane >> 5;
  int hl = lane & 31;
  int beg = rowptr[nd], end = rowptr[nd + 1];
  float4 sg = make_float4(0.f, 0.f, 0.f, 0.f);
  float4 sc = make_float4(0.f, 0.f, 0.f, 0.f);
  int j = beg + half;
  for (; j + 6 < end; j += 8) {
    int s0 = csrc[j], s1 = csrc[j + 2], s2 = csrc[j + 4], s3 = csrc[j + 6];
    float w0 = dinv[s0], w1 = dinv[s1], w2 = dinv[s2], w3 = dinv[s3];
    ushort4 v0 = *(const ushort4*)(xb + (long)s0 * D + 4 * hl);
    ushort4 v1 = *(const ushort4*)(xb + (long)s1 * D + 4 * hl);
    ushort4 v2 = *(const ushort4*)(xb + (long)s2 * D + 4 * hl);
    ushort4 v3 = *(const ushort4*)(xb + (long)s3 * D + 4 * hl);
    float a0 = bf2f(v0.x), a1 = bf2f(v0.y), a2 = bf2f(v0.z), a3 = bf2f(v0.w);
    sg.x += a0; sg.y += a1; sg.z += a2; sg.w += a3;
    sc.x = fmaf(w0, a0, sc.x); sc.y = fmaf(w0, a1, sc.y);
    sc.z = fmaf(w0, a2, sc.z); sc.w = fmaf(w0, a3, sc.w);
    a0 = bf2f(v1.x); a1 = bf2f(v1.y); a2 = bf2f(v1.z); a3 = bf2f(v1.w);
    sg.x += a0; sg.y += a1; sg.z += a2; sg.w += a3;
    sc.x = fmaf(w1, a0, sc.x); sc.y = fmaf(w1, a1, sc.y);
    sc.z = fmaf(w1, a2, sc.z); sc.w = fmaf(w1, a3, sc.w);
    a0 = bf2f(v2.x); a1 = bf2f(v2.y); a2 = bf2f(v2.z); a3 = bf2f(v2.w);
    sg.x += a0; sg.y += a1; sg.z += a2; sg.w += a3;
    sc.x = fmaf(w2, a0, sc.x); sc.y = fmaf(w2, a1, sc.y);
    sc.z = fmaf(w2, a2, sc.z); sc.w = fmaf(w2, a3, sc.w);
    a0 = bf2f(v3.x); a1 = bf2f(v3.y); a2 = bf2f(v3.z); a3 = bf2f(v3.w);
    sg.x += a0; sg.y += a1; sg.z += a2; sg.w += a3;
    sc.x = fmaf(w3, a0, sc.x); sc.y = fmaf(w3, a1, sc.y);
    sc.z = fmaf(w3, a2, sc.z); sc.w = fmaf(w3, a3, sc.w);
  }
  for (; j < end; j += 2) {
    int s0 = csrc[j];
    float w0 = dinv[s0];
    ushort4 v0 = *(const ushort4*)(xb + (long)s0 * D + 4 * hl);
    float a0 = bf2f(v0.x), a1 = bf2f(v0.y), a2 = bf2f(v0.z), a3 = bf2f(v0.w);
    sg.x += a0; sg.y += a1; sg.z += a2; sg.w += a3;
    sc.x = fmaf(w0, a0, sc.x); sc.y = fmaf(w0, a1, sc.y);
    sc.z = fmaf(w0, a2, sc.z); sc.w = fmaf(w0, a3, sc.w);
  }
  sg.x += __shfl_xor(sg.x, 32); sg.y += __shfl_xor(sg.y, 32);
  sg.z += __shfl_xor(sg.z, 32); sg.w += __shfl_xor(sg.w, 32);
  sc.x += __shfl_xor(sc.x, 32); sc.y += __shfl_xor(sc.y, 32);
  sc.z += __shfl_xor(sc.z, 32); sc.w += __shfl_xor(sc.w, 32);

  ushort4 us = *(const ushort4*)(xb + (long)nd * D + 4 * hl);
  float x0 = bf2f(us.x), x1 = bf2f(us.y), x2 = bf2f(us.z), x3 = bf2f(us.w);
  float dd = dinv[nd];
  ushort4 o;
  if (half == 0) {
    o.x = f2bf(dd * (sc.x + dd * x0));
    o.y = f2bf(dd * (sc.y + dd * x1));
    o.z = f2bf(dd * (sc.z + dd * x2));
    o.w = f2bf(dd * (sc.w + dd * x3));
    *(ushort4*)(ab + (long)nd * 256 + 4 * hl) = o;
  } else {
    o.x = f2bf(x0 + sg.x);
    o.y = f2bf(x1 + sg.y);
    o.z = f2bf(x2 + sg.z);
    o.w = f2bf(x3 + sg.w);
    *(ushort4*)(ab + (long)nd * 256 + 128 + 4 * hl) = o;
  }
}

// ---------------------------------------------------------------------------
// gemm1': y=0 (GCN): h = relu(Agcn@T1g^T + gb1); p1 = h @ W2gT^T  (two-stage,
//         h via per-wave LDS tile). y=1 (GIN): p2 = Agin@WginT^T + bgin.
// Output pq[node][256] = [p1 | p2] bf16.
// ---------------------------------------------------------------------------
__global__ __launch_bounds__(256) void gemm1_kernel(
    const ushort* __restrict__ ab,
    const ushort* __restrict__ T1g, const ushort* __restrict__ WginT,
    const ushort* __restrict__ W2gT,
    const float* __restrict__ gb1, const float* __restrict__ bgin,
    ushort* __restrict__ pq, int n) {
  __shared__ ushort Ws[128 * 128];
  __shared__ ushort Hs[128 * HS_LD];
  const int y = blockIdx.y;
  const int tid = threadIdx.x;
  const int wave = tid >> 6, lane = tid & 63;
  const int rlo = lane & 15, khi = lane >> 4;
  const int rb = blockIdx.x * 128 + wave * 32;

  // A fragments from global (half y of ab)
  s8v a[2][4];
#pragma unroll
  for (int rt = 0; rt < 2; ++rt) {
    int row = rb + rt * 16 + rlo;
    row = row < n ? row : n - 1;
    const ushort* p = ab + (long)row * 256 + y * 128 + khi * 8;
#pragma unroll
    for (int ks = 0; ks < 4; ++ks) a[rt][ks] = *(const s8v*)(p + ks * 32);
  }

  // stage B1 (T1g for GCN, folded WginT for GIN)
  {
    const ushort* W = y ? WginT : T1g;
#pragma unroll
    for (int j = 0; j < 8; ++j) {
      int q = tid + 256 * j;
      int c = q >> 4, kc = q & 15;
      *(s8v*)&Ws[c * 128 + ((kc ^ (c & 7)) << 3)] = *(const s8v*)(W + c * 128 + kc * 8);
    }
  }
  __syncthreads();

  f4v acc[2][8];
#pragma unroll
  for (int rt = 0; rt < 2; ++rt)
#pragma unroll
    for (int ct = 0; ct < 8; ++ct) acc[rt][ct] = (f4v){0.f, 0.f, 0.f, 0.f};

#pragma unroll
  for (int ks = 0; ks < 4; ++ks) {
#pragma unroll
    for (int ct = 0; ct < 8; ++ct) {
      int c = ct * 16 + rlo;
      int kc = ks * 4 + khi;
      s8v b = *(const s8v*)&Ws[c * 128 + ((kc ^ (c & 7)) << 3)];
      acc[0][ct] = __builtin_amdgcn_mfma_f32_16x16x32_bf16(a[0][ks], b, acc[0][ct], 0, 0, 0);
      acc[1][ct] = __builtin_amdgcn_mfma_f32_16x16x32_bf16(a[1][ks], b, acc[1][ct], 0, 0, 0);
    }
  }

  if (y == 1) {
    // epilogue: p2 = acc + bgin -> pq cols 128..255
#pragma unroll
    for (int ct = 0; ct < 8; ++ct) {
      int col = ct * 16 + rlo;
      float bb = bgin[col];
#pragma unroll
      for (int rt = 0; rt < 2; ++rt) {
#pragma unroll
        for (int i = 0; i < 4; ++i) {
          int row = rb + rt * 16 + 4 * khi + i;
          if (row < n)
            pq[(long)row * 256 + 128 + col] = f2bf(acc[rt][ct][i] + bb);
        }
      }
    }
    return;
  }

  // ---- GCN stage 2 ----
  __syncthreads();  // all waves done reading Ws (stage-1 weights)
  // write h = relu(acc + gb1) into per-wave LDS tile; restage Ws with W2gT
#pragma unroll
  for (int ct = 0; ct < 8; ++ct) {
    int col = ct * 16 + rlo;
    float bb = gb1[col];
#pragma unroll
    for (int rt = 0; rt < 2; ++rt) {
#pragma unroll
      for (int i = 0; i < 4; ++i) {
        int r = wave * 32 + rt * 16 + 4 * khi + i;
        Hs[r * HS_LD + col] = f2bf(fmaxf(acc[rt][ct][i] + bb, 0.f));
      }
    }
  }
#pragma unroll
  for (int j = 0; j < 8; ++j) {
    int q = tid + 256 * j;
    int c = q >> 4, kc = q & 15;
    *(s8v*)&Ws[c * 128 + ((kc ^ (c & 7)) << 3)] = *(const s8v*)(W2gT + c * 128 + kc * 8);
  }
  __syncthreads();

  s8v a2[2][4];
#pragma unroll
  for (int rt = 0; rt < 2; ++rt) {
    int r = wave * 32 + rt * 16 + rlo;
#pragma unroll
    for (int ks = 0; ks < 4; ++ks)
      a2[rt][ks] = *(const s8v*)&Hs[r * HS_LD + (ks * 4 + khi) * 8];
  }

  f4v acc2[2][8];
#pragma unroll
  for (int rt = 0; rt < 2; ++rt)
#pragma unroll
    for (int ct = 0; ct < 8; ++ct) acc2[rt][ct] = (f4v){0.f, 0.f, 0.f, 0.f};

#pragma unroll
  for (int ks = 0; ks < 4; ++ks) {
#pragma unroll
    for (int ct = 0; ct < 8; ++ct) {
      int c = ct * 16 + rlo;
      int kc = ks * 4 + khi;
      s8v b = *(const s8v*)&Ws[c * 128 + ((kc ^ (c & 7)) << 3)];
      acc2[0][ct] = __builtin_amdgcn_mfma_f32_16x16x32_bf16(a2[0][ks], b, acc2[0][ct], 0, 0, 0);
      acc2[1][ct] = __builtin_amdgcn_mfma_f32_16x16x32_bf16(a2[1][ks], b, acc2[1][ct], 0, 0, 0);
    }
  }

#pragma unroll
  for (int ct = 0; ct < 8; ++ct) {
    int col = ct * 16 + rlo;
#pragma unroll
    for (int rt = 0; rt < 2; ++rt) {
#pragma unroll
      for (int i = 0; i < 4; ++i) {
        int row = rb + rt * 16 + 4 * khi + i;
        if (row < n)
          pq[(long)row * 256 + col] = f2bf(acc2[rt][ct][i]);
      }
    }
  }
}

// ---------------------------------------------------------------------------
// gather B': final output. pq[node][256]=[p1|p2]; lanes 0-31 aggregate GCN
// (dinv-scaled p1), lanes 32-63 GIN (p2); combine shfl_xor(32); +btot; f32 out.
// ---------------------------------------------------------------------------
__global__ __launch_bounds__(256) void gatherB_kernel(
    const ushort* __restrict__ pq, const float* __restrict__ dinv,
    const int* __restrict__ rowptr, const int* __restrict__ csrc,
    const float* __restrict__ btot, float* __restrict__ out, int n) {
  int nd = blockIdx.x * 4 + (threadIdx.x >> 6);
  if (nd >= n) return;
  int lane = threadIdx.x & 63;
  int half = lane >> 5;
  int hl = lane & 31;
  int beg = rowptr[nd], end = rowptr[nd + 1];
  float4 s = make_float4(0.f, 0.f, 0.f, 0.f);
  int j = beg;
  for (; j + 3 < end; j += 4) {
    int s0 = csrc[j], s1 = csrc[j + 1], s2 = csrc[j + 2], s3 = csrc[j + 3];
    float w0 = dinv[s0], w1 = dinv[s1], w2 = dinv[s2], w3 = dinv[s3];
    ushort4 v0 = *(const ushort4*)(pq + (long)s0 * 256 + lane * 4);
    ushort4 v1 = *(const ushort4*)(pq + (long)s1 * 256 + lane * 4);
    ushort4 v2 = *(const ushort4*)(pq + (long)s2 * 256 + lane * 4);
    ushort4 v3 = *(const ushort4*)(pq + (long)s3 * 256 + lane * 4);
    float c0 = half ? 1.f : w0;
    float c1 = half ? 1.f : w1;
    float c2 = half ? 1.f : w2;
    float c3 = half ? 1.f : w3;
    s.x = fmaf(c0, bf2f(v0.x), s.x); s.y = fmaf(c0, bf2f(v0.y), s.y);
    s.z = fmaf(c0, bf2f(v0.z), s.z); s.w = fmaf(c0, bf2f(v0.w), s.w);
    s.x = fmaf(c1, bf2f(v1.x), s.x); s.y = fmaf(c1, bf2f(v1.y), s.y);
    s.z = fmaf(c1, bf2f(v1.z), s.z); s.w = fmaf(c1, bf2f(v1.w), s.w);
    s.x = fmaf(c2, bf2f(v2.x), s.x); s.y = fmaf(c2, bf2f(v2.y), s.y);
    s.z = fmaf(c2, bf2f(v2.z), s.z); s.w = fmaf(c2, bf2f(v2.w), s.w);
    s.x = fmaf(c3, bf2f(v3.x), s.x); s.y = fmaf(c3, bf2f(v3.y), s.y);
    s.z = fmaf(c3, bf2f(v3.z), s.z); s.w = fmaf(c3, bf2f(v3.w), s.w);
  }
  for (; j < end; ++j) {
    int s0 = csrc[j];
    float w0 = dinv[s0];
    ushort4 v0 = *(const ushort4*)(pq + (long)s0 * 256 + lane * 4);
    float c0 = half ? 1.f : w0;
    s.x = fmaf(c0, bf2f(v0.x), s.x); s.y = fmaf(c0, bf2f(v0.y), s.y);
    s.z = fmaf(c0, bf2f(v0.z), s.z); s.w = fmaf(c0, bf2f(v0.w), s.w);
  }
  ushort4 u = *(const ushort4*)(pq + (long)nd * 256 + lane * 4);
  float dd = dinv[nd];
  float4 o;
  if (half == 0) {  // GCN: dinv*(sum + dinv*self)
    o.x = dd * (s.x + dd * bf2f(u.x));
    o.y = dd * (s.y + dd * bf2f(u.y));
    o.z = dd * (s.z + dd * bf2f(u.z));
    o.w = dd * (s.w + dd * bf2f(u.w));
  } else {          // GIN: sum + self
    o.x = s.x + bf2f(u.x);
    o.y = s.y + bf2f(u.y);
    o.z = s.z + bf2f(u.z);
    o.w = s.w + bf2f(u.w);
  }
  o.x += __shfl_xor(o.x, 32);
  o.y += __shfl_xor(o.y, 32);
  o.z += __shfl_xor(o.z, 32);
  o.w += __shfl_xor(o.w, 32);
  if (half == 0) {
    float4 bt = *(const float4*)(btot + 4 * hl);
    o.x += bt.x; o.y += bt.y; o.z += bt.z; o.w += bt.w;
    *(float4*)(out + (long)nd * D + 4 * hl) = o;
  }
}

// ---------------------------------------------------------------------------
extern "C" void kernel_launch(void* const* d_in, const int* in_sizes, int n_in,
                              void* d_out, int out_size, void* d_ws, size_t ws_size,
                              hipStream_t stream) {
  const float* x   = (const float*)d_in[0];
  const int*   ei  = (const int*)d_in[1];
  const float* gw1 = (const float*)d_in[2];
  const float* gb1 = (const float*)d_in[3];
  const float* gw2 = (const float*)d_in[4];
  const float* gb2 = (const float*)d_in[5];
  const float* iw1 = (const float*)d_in[6];
  const float* ib1 = (const float*)d_in[7];
  const float* iw2 = (const float*)d_in[8];
  const float* ib2 = (const float*)d_in[9];
  const float* lw  = (const float*)d_in[10];
  const float* lb  = (const float*)d_in[11];
  const float* fw  = (const float*)d_in[12];
  const float* fb  = (const float*)d_in[13];
  float* out = (float*)d_out;

  const int n = in_sizes[0] / D;
  const int E = in_sizes[1] / 2;
  const int* src = ei;
  const int* dst = ei + E;
  const int nb = (n + 255) / 256;
  const long ND = (long)n * D;

  char* p = (char*)d_ws;
  auto alloc = [&](size_t bytes) {
    char* r = p;
    p += (bytes + 255) & ~(size_t)255;
    return r;
  };
  int* ideg    = (int*)alloc((size_t)n * 4);
  int* incl    = (int*)alloc((size_t)n * 4);
  int* rowptr  = (int*)alloc((size_t)(n + 1) * 4);
  int* bsum    = (int*)alloc(1024 * 4);
  int* pos     = (int*)alloc((size_t)E * 4);
  int* csrc    = (int*)alloc((size_t)E * 4);
  float* dinv  = (float*)alloc((size_t)n * 4);
  float* LF    = (float*)alloc(16384 * 4);
  float* M2i   = (float*)alloc(16384 * 4);
  float* btot  = (float*)alloc(128 * 4);
  float* bgin  = (float*)alloc(128 * 4);
  ushort* xb   = (ushort*)alloc(ND * 2);
  ushort* T1g   = (ushort*)alloc(16384 * 2);
  ushort* WginT = (ushort*)alloc(16384 * 2);
  ushort* W2gT  = (ushort*)alloc(16384 * 2);
  ushort* ab   = (ushort*)alloc(2 * ND * 2);  // gatherA out / gemm1 in
  ushort* pq   = (ushort*)alloc(2 * ND * 2);  // gemm1 out / gatherB in

  hipMemsetAsync(ideg, 0, (size_t)n * 4, stream);

  // front end: degpos | xcvt | LF | gw1-transpose
  megaA_kernel<<<5376, 256, 0, stream>>>(dst, ideg, pos, E, x, xb, ND, lw, fw, LF, gw1, T1g);
  // scan1 | M2i | W2gT | btot
  scanP_kernel<<<nb + 129, 256, 0, stream>>>(ideg, incl, bsum, n, nb, iw2, gw2, LF,
                                             M2i, W2gT, gb2, ib2, lb, fw, fb, btot);
  // scan2 | WginT | bgin
  scan2F_kernel<<<66, 256, 0, stream>>>(bsum, nb, iw1, M2i, WginT, ib1, bgin);
  scan3_kernel<<<nb, 256, 0, stream>>>(ideg, incl, bsum, rowptr, dinv, n, E);
  scatter_kernel<<<2048, 256, 0, stream>>>(src, dst, rowptr, pos, csrc, E);

  // layer 1 aggregation
  gatherA_kernel<<<(n + 3) / 4, 256, 0, stream>>>(xb, dinv, rowptr, csrc, ab, n);
  // fused GEMMs: p1 = relu(Agcn@W1+b1)@(gw2@LF); p2 = Agin@(iw1@iw2@LF)+bgin
  const int nblk = (n + 127) / 128;
  gemm1_kernel<<<dim3(nblk, 2), 256, 0, stream>>>(ab, T1g, WginT, W2gT, gb1, bgin, pq, n);
  // final aggregation writes output directly
  gatherB_kernel<<<(n + 3) / 4, 256, 0, stream>>>(pq, dinv, rowptr, csrc, btot, out, n);
}